// Round 13
// baseline (232.973 us; speedup 1.0000x reference)
//
#include <hip/hip_runtime.h>
#include <math.h>

// Problem constants
#define Bn 4
#define Tn 2048
#define Cn 1024
#define Hn 16
#define HDn 64
#define Mn (Bn * Tn)  // 8192 tokens

typedef unsigned short u16;
typedef unsigned int u32;
typedef __attribute__((ext_vector_type(8))) short bf16x8;        // 8 bf16 = 4 VGPRs
typedef __attribute__((ext_vector_type(8))) unsigned short us8;  // 16B chunk
typedef __attribute__((ext_vector_type(4))) float f32x4;         // 16x16 MFMA acc
typedef __attribute__((ext_vector_type(16))) float f32x16;       // 32x32 MFMA acc
typedef __attribute__((ext_vector_type(4))) unsigned int u32x4;

__device__ __forceinline__ float b2f(u16 u) {
    return __uint_as_float(((u32)u) << 16);
}
__device__ __forceinline__ u16 f2b(float f) {
    u32 u = __float_as_uint(f);
    return (u16)((u + 0x7FFFu + ((u >> 16) & 1u)) >> 16);  // RNE
}
__device__ __forceinline__ u32 cvtpk(float a, float b) {   // {lo:bf16(a), hi:bf16(b)}
    u32 d;
    asm("v_cvt_pk_bf16_f32 %0, %1, %2" : "=v"(d) : "v"(a), "v"(b));
    return d;
}
// v_permlane32_swap_b32: a[32..63] <-> b[0..31]
__device__ __forceinline__ void pswap(u32& a, u32& b) {
    asm("v_permlane32_swap_b32 %0, %1" : "+v"(a), "+v"(b));
}
__device__ __forceinline__ float max3f(float a, float b, float c) {
    float d;
    asm("v_max3_f32 %0, %1, %2, %3" : "=v"(d) : "v"(a), "v"(b), "v"(c));
    return d;
}
#define EXP2R(x) __builtin_amdgcn_exp2f(x)   // raw v_exp_f32 (|x| < 126 here)

// XCD-grouped work id from flat block id (requires gridDim.x % 8 == 0).
__device__ __forceinline__ int xcd_work(int bid, int nwg) {
    return (bid & 7) * (nwg >> 3) + (bid >> 3);
}

// global_load_lds, width 16 (literal size required)
#define GLL(srcp, dstp)                                                     \
    __builtin_amdgcn_global_load_lds(                                       \
        (const __attribute__((address_space(1))) u32*)(srcp),               \
        (__attribute__((address_space(3))) u32*)(dstp), 16, 0, 0)

// counted vmcnt waits (T4): never drain to 0 in the main loop
#define WAITCNT2() asm volatile("s_waitcnt vmcnt(2)" ::: "memory")
#define WAITCNT4() asm volatile("s_waitcnt vmcnt(4)" ::: "memory")
#define WAITCNT0() asm volatile("s_waitcnt vmcnt(0)" ::: "memory")

// ---------------------------------------------------------------------------
// fp32 -> bf16 elementwise convert (grid-stride, 2048 blocks)
// ---------------------------------------------------------------------------
__global__ __launch_bounds__(256) void cvt_f32_bf16_kernel(
    const float4* __restrict__ in, ushort4* __restrict__ out, int n4)
{
    for (int i = blockIdx.x * 256 + threadIdx.x; i < n4; i += gridDim.x * 256) {
        float4 v = in[i];
        ushort4 o;
        o.x = f2b(v.x); o.y = f2b(v.y); o.z = f2b(v.z); o.w = f2b(v.w);
        out[i] = o;
    }
}

// ---------------------------------------------------------------------------
// Transpose + convert: in [R,Cc] fp32 -> out [Cc,R] bf16. 32x32 LDS tiles.
// ---------------------------------------------------------------------------
__global__ __launch_bounds__(256) void transpose_cvt_kernel(
    const float* __restrict__ in, u16* __restrict__ out, int R, int Cc)
{
    __shared__ u16 t[32][33];
    const int c0 = blockIdx.x * 32, r0 = blockIdx.y * 32;
    const int tx = threadIdx.x & 31, ty = threadIdx.x >> 5;  // 32 x 8
    #pragma unroll
    for (int i = 0; i < 32; i += 8)
        t[ty + i][tx] = f2b(in[(size_t)(r0 + ty + i) * Cc + c0 + tx]);
    __syncthreads();
    #pragma unroll
    for (int i = 0; i < 32; i += 8)
        out[(size_t)(c0 + ty + i) * R + r0 + tx] = t[tx][ty + i];
}

// ---------------------------------------------------------------------------
// bf16 MFMA GEMM v5 (A-from-global): Out[M,N] = A[M,K] @ BT[N,K]^T + bias[N]
// 128x128 block, BK=32, 4 waves, wave tile 64x64.
// A-fragments loaded DIRECTLY from global (L2-resident panel) into registers
// each K-step -> no A staging, no A ds_reads (LDS pipe load cut 3x).
// B staged via global_load_lds, 3 buffers, counted vmcnt(2) (2 GLL/thr/stage).
// 24KB LDS + ~116 VGPR -> 4 blocks/CU (16 waves, 2x occupancy of R12).
// No setprio (hurts lockstep GEMM, m190).
// QKV_MODE: output cols >= 2048 (V section) written transposed to vT[b][c][t].
// ---------------------------------------------------------------------------
template <bool OUT_BF16, bool QKV_MODE>
__global__ __launch_bounds__(256, 4) void gemm_ag_kernel(
    const u16* __restrict__ A, const u16* __restrict__ BT,
    const float* __restrict__ bias,
    u16* __restrict__ outb, float* __restrict__ outf, u16* __restrict__ vTout,
    int N, int K, int nx)
{
    __shared__ u16 Bl[3][128 * 32];   // 8KB per buffer

    const int tid = threadIdx.x;
    const int workid = xcd_work(blockIdx.x, gridDim.x);
    const int brow = (workid / nx) * 128;
    const int bcol = (workid % nx) * 128;
    const int w  = tid >> 6;
    const int wr = w >> 1, wc = w & 1;
    const int l  = tid & 63;
    const int lr = l & 15;
    const int lk = (l >> 4) << 3;     // u16 k-offset (chunk l>>4)

    // B staging: round j covers rows j*64 + w*16 + (l>>2), chunk (l&3)*8 u16.
    const int srow = l >> 2;
    const int schk = (l & 3) << 3;

    f32x4 acc[4][4];
    #pragma unroll
    for (int m = 0; m < 4; ++m)
        #pragma unroll
        for (int n = 0; n < 4; ++n) acc[m][n] = (f32x4){0.f, 0.f, 0.f, 0.f};

    // 2 GLL per thread per stage (j = 0,1); LDS dst linear (wave base + lane*16B)
    #define STAGE_B(k0, bufi)                                                  \
        do {                                                                   \
            GLL(&BT[(size_t)(bcol +      w * 16 + srow) * K + (k0) + schk],    \
                &Bl[bufi][(w * 16) * 32]);                                     \
            GLL(&BT[(size_t)(bcol + 64 + w * 16 + srow) * K + (k0) + schk],    \
                &Bl[bufi][(64 + w * 16) * 32]);                                \
        } while (0)

    const int T = K >> 5;
    STAGE_B(0, 0);
    STAGE_B(32, 1);

    const u16* Arow = A + (size_t)(brow + wr * 64 + lr) * K + lk;

    int cur = 0;
    for (int t = 0; t < T; ++t) {
        WAITCNT2();                     // own stage(t) landed (stage(t+1) in flight)
        __builtin_amdgcn_s_barrier();   // all waves' stage(t) landed

        const int k0 = t << 5;
        // A fragments straight from global (64B-line coalesced, L2-hot panel)
        bf16x8 a[4];
        #pragma unroll
        for (int m = 0; m < 4; ++m)
            a[m] = *(const bf16x8*)(Arow + (size_t)(m * 16) * K + k0);

        // B fragments from LDS
        bf16x8 b[4];
        #pragma unroll
        for (int n = 0; n < 4; ++n)
            b[n] = *(const bf16x8*)&Bl[cur][(wc * 64 + n * 16 + lr) * 32 + lk];

        __builtin_amdgcn_sched_barrier(0);  // keep GLLs BELOW the a[]/b[] loads
        if (t + 2 < T) {
            const int nb = cur + 2 >= 3 ? cur - 1 : cur + 2;
            STAGE_B((t + 2) << 5, nb);
        }
        __builtin_amdgcn_sched_barrier(0);  // keep MFMAs BELOW the GLL issue

        #pragma unroll
        for (int m = 0; m < 4; ++m)
            #pragma unroll
            for (int n = 0; n < 4; ++n)
                acc[m][n] = __builtin_amdgcn_mfma_f32_16x16x32_bf16(
                    a[m], b[n], acc[m][n], 0, 0, 0);

        cur = cur == 2 ? 0 : cur + 1;
    }
    #undef STAGE_B

    // Epilogue. C/D layout: col = lane&15, row = (lane>>4)*4 + reg.
    const int orow0 = brow + wr * 64 + ((l >> 4) << 2);
    const int ocol0 = bcol + wc * 64 + lr;
    if (QKV_MODE && bcol >= 2048) {
        #pragma unroll
        for (int n = 0; n < 4; ++n) {
            const int c = ocol0 + n * 16 - 2048;
            const float bv = bias[ocol0 + n * 16];
            #pragma unroll
            for (int m = 0; m < 4; ++m) {
                const int row0 = orow0 + m * 16;
                const int bb = row0 >> 11, t0 = row0 & 2047;
                ushort4 pk;
                pk.x = f2b(acc[m][n][0] + bv);
                pk.y = f2b(acc[m][n][1] + bv);
                pk.z = f2b(acc[m][n][2] + bv);
                pk.w = f2b(acc[m][n][3] + bv);
                *(ushort4*)&vTout[((size_t)bb * Cn + c) * Tn + t0] = pk;
            }
        }
    } else {
        #pragma unroll
        for (int n = 0; n < 4; ++n) {
            const int col = ocol0 + n * 16;
            const float bv = bias[col];
            #pragma unroll
            for (int m = 0; m < 4; ++m) {
                #pragma unroll
                for (int r = 0; r < 4; ++r) {
                    const int row = orow0 + m * 16 + r;
                    const float v = acc[m][n][r] + bv;
                    if (OUT_BF16) outb[(size_t)row * N + col] = f2b(v);
                    else          outf[(size_t)row * N + col] = v;
                }
            }
        }
    }
}

// ---------------------------------------------------------------------------
// MFMA flash attention v8 (causal) - unchanged from round 12 (verified).
// 32x32 MFMA, in-register softmax (T12), triple-buffered K/V, counted vmcnt,
// raw v_exp_f32, fmaf-folded scale, v_max3 tree.
// ---------------------------------------------------------------------------
__global__ __launch_bounds__(256, 2) void attn_mfma8_kernel(
    const u16* __restrict__ qkvb, const u16* __restrict__ vT,
    u16* __restrict__ yb)
{
    __shared__ u16 Kb[3][64 * 64];   // [k-row][d-chunk swizzled]
    __shared__ u16 Vb[3][64 * 64];   // [d-row][k-chunk swizzled]

    const int tid = threadIdx.x;
    const int w   = tid >> 6;        // wave 0..3
    const int l   = tid & 63;
    const int q31 = l & 31;          // q (QK^T B-col) / d (PV B-col)
    const int hi  = l >> 5;
    const int work = xcd_work(blockIdx.x, 512);
    const int pr  = work & 7;        // pair index 0..7
    const int bh  = work >> 3;       // 8 bh per XCD
    const int b   = bh >> 4, h = bh & 15;

    const float S2 = 0.18033688f;    // 0.125 * log2(e)

    const u16* Kg = qkvb + (size_t)(b * Tn) * (3 * Cn) + Cn + h * HDn;
    const u16* Vg = vT + (size_t)bh * HDn * Tn;

    const int srow = l >> 3;                   // staging row 0..7
    const int schk = ((l & 7) ^ srow) << 3;    // swizzled source chunk (u16)
    const int rloc = w * 16;                   // wave's staging row slice
    const int rsw8 = q31 & 7;                  // read-side XOR key (chunk idx)

    #define STAGE_A(kt, bufi)                                                  \
        do {                                                                   \
            _Pragma("unroll")                                                  \
            for (int jc = 0; jc < 2; ++jc) {                                   \
                const int rr = rloc + jc * 8;                                  \
                GLL(Kg + (size_t)((kt) * 64 + rr + srow) * (3 * Cn) + schk,    \
                    &Kb[bufi][rr * 64]);                                       \
                GLL(Vg + (size_t)(rr + srow) * Tn + (kt) * 64 + schk,          \
                    &Vb[bufi][rr * 64]);                                       \
            }                                                                  \
        } while (0)

    #pragma unroll 1
    for (int half = 0; half < 2; ++half) {
        const int qt = half ? (15 - pr) : pr;   // 128-row tile index
        const int ktmax = 2 * qt + 2;
        const int qrow0 = qt * 128 + w * 32;    // wave's first q row
        const int qglob = qrow0 + q31;          // this lane's q row

        // Q B-frags: qf[c] = Q[qglob][c*16 + hi*8 .. +7]
        const u16* Qp = qkvb + (size_t)(b * Tn + qglob) * (3 * Cn)
                        + h * HDn + hi * 8;
        bf16x8 qf[4];
        #pragma unroll
        for (int c = 0; c < 4; ++c) qf[c] = *(const bf16x8*)(Qp + c * 16);

        f32x16 O0, O1;
        #pragma unroll
        for (int r = 0; r < 16; ++r) { O0[r] = 0.f; O1[r] = 0.f; }
        float m = -INFINITY, ls = 0.f;

        STAGE_A(0, 0);
        STAGE_A(1, 1);

        int cur = 0;
        for (int kt = 0; kt < ktmax; ++kt) {
            if (kt < ktmax - 1) WAITCNT4();
            else                WAITCNT0();
            __builtin_amdgcn_s_barrier();

            if (kt + 2 < ktmax) {
                const int nb = cur + 2 >= 3 ? cur - 1 : cur + 2;
                STAGE_A(kt + 2, nb);
            }
            const u16* Kc = Kb[cur];
            const u16* Vc = Vb[cur];

            if (kt * 64 <= qrow0 + 31) {   // wave has unmasked work
                // S^T = K Q^T : two 32x32 tiles (k 0..31, 32..63)
                f32x16 S0, S1;
                #pragma unroll
                for (int r = 0; r < 16; ++r) { S0[r] = 0.f; S1[r] = 0.f; }
                __builtin_amdgcn_s_setprio(1);
                #pragma unroll
                for (int c = 0; c < 4; ++c) {
                    const int co = ((2 * c + hi) ^ rsw8) << 3;
                    const bf16x8 k0 = *(const bf16x8*)&Kc[q31 * 64 + co];
                    const bf16x8 k1 = *(const bf16x8*)&Kc[(32 + q31) * 64 + co];
                    S0 = __builtin_amdgcn_mfma_f32_32x32x16_bf16(k0, qf[c], S0, 0, 0, 0);
                    S1 = __builtin_amdgcn_mfma_f32_32x32x16_bf16(k1, qf[c], S1, 0, 0, 0);
                }
                __builtin_amdgcn_s_setprio(0);

                // causal mask (diagonal-straddling steps only)
                if (kt * 64 + 63 > qrow0) {
                    #pragma unroll
                    for (int r = 0; r < 16; ++r) {
                        const int kl = kt * 64 + (r & 3) + 8 * (r >> 2) + 4 * hi;
                        if (kl > qglob)      S0[r] = -INFINITY;
                        if (kl + 32 > qglob) S1[r] = -INFINITY;
                    }
                }

                // row max: v_max3 tree (depth 4) + 1 cross-half shuffle
                float a0 = max3f(S0[0],  S0[1],  S0[2]);
                float a1 = max3f(S0[3],  S0[4],  S0[5]);
                float a2 = max3f(S0[6],  S0[7],  S0[8]);
                float a3 = max3f(S0[9],  S0[10], S0[11]);
                float a4 = max3f(S0[12], S0[13], S0[14]);
                float a5 = max3f(S0[15], S1[0],  S1[1]);
                float a6 = max3f(S1[2],  S1[3],  S1[4]);
                float a7 = max3f(S1[5],  S1[6],  S1[7]);
                float a8 = max3f(S1[8],  S1[9],  S1[10]);
                float a9 = max3f(S1[11], S1[12], S1[13]);
                float aA = fmaxf(S1[14], S1[15]);
                float b0 = max3f(a0, a1, a2);
                float b1 = max3f(a3, a4, a5);
                float b2 = max3f(a6, a7, a8);
                float b3 = fmaxf(a9, aA);
                float mt = fmaxf(fmaxf(b0, b1), fmaxf(b2, b3));
                mt = fmaxf(mt, __shfl_xor(mt, 32));

                // defer-max (first active step always triggers: m = -inf)
                float lscale = 1.f;
                if (__any(mt > m + 64.f)) {
                    const float mn = fmaxf(m, mt);
                    const float alpha = EXP2R((m - mn) * S2);
                    m = mn; lscale = alpha;
                    #pragma unroll
                    for (int r = 0; r < 16; ++r) {
                        const int qloc = (r & 3) + 8 * (r >> 2) + 4 * hi;
                        const float ar = __shfl(alpha, qloc);
                        O0[r] *= ar; O1[r] *= ar;
                    }
                }

                // P = exp2(S*S2 - m*S2) via fmaf + raw v_exp_f32
                const float nms2 = -m * S2;
                float lt0 = 0.f, lt1 = 0.f;
                u32 w0[8], w1[8];
                #pragma unroll
                for (int i = 0; i < 8; ++i) {
                    const float p0 = EXP2R(fmaf(S0[2 * i],     S2, nms2));
                    const float p1 = EXP2R(fmaf(S0[2 * i + 1], S2, nms2));
                    const float p2 = EXP2R(fmaf(S1[2 * i],     S2, nms2));
                    const float p3 = EXP2R(fmaf(S1[2 * i + 1], S2, nms2));
                    lt0 += (p0 + p1);
                    lt1 += (p2 + p3);
                    w0[i] = cvtpk(p0, p1);
                    w1[i] = cvtpk(p2, p3);
                }
                float lt = lt0 + lt1;
                lt += __shfl_xor(lt, 32);
                ls = ls * lscale + lt;

                // O += P @ V : assemble A-frags via permlane32_swap, B from Vs
                __builtin_amdgcn_s_setprio(1);
                #pragma unroll
                for (int t2 = 0; t2 < 2; ++t2) {
                    #pragma unroll
                    for (int c1 = 0; c1 < 2; ++c1) {
                        u32 a0w = t2 ? w1[4 * c1 + 0] : w0[4 * c1 + 0];
                        u32 b0w = t2 ? w1[4 * c1 + 2] : w0[4 * c1 + 2];
                        u32 a1w = t2 ? w1[4 * c1 + 1] : w0[4 * c1 + 1];
                        u32 b1w = t2 ? w1[4 * c1 + 3] : w0[4 * c1 + 3];
                        pswap(a0w, b0w);   // -> frag words 0 and 2
                        pswap(a1w, b1w);   // -> frag words 1 and 3
                        u32x4 fr; fr.x = a0w; fr.y = a1w; fr.z = b0w; fr.w = b1w;
                        const bf16x8 pf = __builtin_bit_cast(bf16x8, fr);
                        const int c = t2 * 2 + c1;
                        const int co = ((2 * c + hi) ^ rsw8) << 3;
                        const bf16x8 v0 = *(const bf16x8*)&Vc[q31 * 64 + co];
                        const bf16x8 v1 = *(const bf16x8*)&Vc[(32 + q31) * 64 + co];
                        O0 = __builtin_amdgcn_mfma_f32_32x32x16_bf16(pf, v0, O0, 0, 0, 0);
                        O1 = __builtin_amdgcn_mfma_f32_32x32x16_bf16(pf, v1, O1, 0, 0, 0);
                    }
                }
                __builtin_amdgcn_s_setprio(0);
            }

            cur = cur == 2 ? 0 : cur + 1;
        }

        // all waves done with LDS before next half's prologue restages
        __builtin_amdgcn_s_barrier();

        // epilogue: O row r -> q = qrow0 + (r&3)+8*(r>>2)+4*hi, col = d
        #pragma unroll
        for (int r = 0; r < 16; ++r) {
            const int qloc = (r & 3) + 8 * (r >> 2) + 4 * hi;
            const float inv = __builtin_amdgcn_rcpf(__shfl(ls, qloc));
            u16* yp = yb + (size_t)(b * Tn + qrow0 + qloc) * Cn + h * HDn + q31;
            yp[0]  = f2b(O0[r] * inv);
            yp[32] = f2b(O1[r] * inv);
        }
    }
    #undef STAGE_A
}

// ---------------------------------------------------------------------------
extern "C" void kernel_launch(void* const* d_in, const int* in_sizes, int n_in,
                              void* d_out, int out_size, void* d_ws, size_t ws_size,
                              hipStream_t stream)
{
    const float* x      = (const float*)d_in[0];
    const float* W_attn = (const float*)d_in[1];
    const float* b_attn = (const float*)d_in[2];
    const float* W_proj = (const float*)d_in[3];
    const float* b_proj = (const float*)d_in[4];
    float* out = (float*)d_out;

    // Workspace (bf16): xb | WaT | WpT | qkvb | yb | vT  (~108 MB)
    u16* xb   = (u16*)d_ws;
    u16* WaT  = xb   + (size_t)Mn * Cn;
    u16* WpT  = WaT  + (size_t)3 * Cn * Cn;
    u16* qkvb = WpT  + (size_t)Cn * Cn;
    u16* yb   = qkvb + (size_t)Mn * 3 * Cn;
    u16* vT   = yb   + (size_t)Mn * Cn;

    cvt_f32_bf16_kernel<<<2048, 256, 0, stream>>>(
        (const float4*)x, (ushort4*)xb, Mn * Cn / 4);

    transpose_cvt_kernel<<<dim3(3 * Cn / 32, Cn / 32), 256, 0, stream>>>(
        W_attn, WaT, Cn, 3 * Cn);
    transpose_cvt_kernel<<<dim3(Cn / 32, Cn / 32), 256, 0, stream>>>(
        W_proj, WpT, Cn, Cn);

    // qkv = x @ W_attn + b_attn; Q/K -> qkvb rows, V -> vT (fused transpose)
    // grid 64 x 24 = 1536 blocks (4/CU target), XCD-grouped
    gemm_ag_kernel<true, true><<<64 * 24, 256, 0, stream>>>(
        xb, WaT, b_attn, qkvb, nullptr, vT, 3 * Cn, Cn, 24);

    // causal MFMA attention -> yb (bf16); grid 512, XCD-grouped
    attn_mfma8_kernel<<<512, 256, 0, stream>>>(qkvb, vT, yb);

    // out = y @ W_proj + b_proj (f32 out); grid 64 x 8 = 512
    gemm_ag_kernel<false, false><<<64 * 8, 256, 0, stream>>>(
        yb, WpT, b_proj, nullptr, out, nullptr, Cn, Cn, 8);
}

// Round 14
// 199.996 us; speedup vs baseline: 1.1649x; 1.1649x over previous
//
#include <hip/hip_runtime.h>
#include <math.h>

// Problem constants
#define Bn 4
#define Tn 2048
#define Cn 1024
#define Hn 16
#define HDn 64
#define Mn (Bn * Tn)  // 8192 tokens

typedef unsigned short u16;
typedef unsigned int u32;
typedef __attribute__((ext_vector_type(8))) short bf16x8;        // 8 bf16 = 4 VGPRs
typedef __attribute__((ext_vector_type(8))) unsigned short us8;  // 16B chunk
typedef __attribute__((ext_vector_type(4))) float f32x4;         // 16x16 MFMA acc
typedef __attribute__((ext_vector_type(16))) float f32x16;       // 32x32 MFMA acc
typedef __attribute__((ext_vector_type(4))) unsigned int u32x4;

__device__ __forceinline__ float b2f(u16 u) {
    return __uint_as_float(((u32)u) << 16);
}
__device__ __forceinline__ u16 f2b(float f) {
    u32 u = __float_as_uint(f);
    return (u16)((u + 0x7FFFu + ((u >> 16) & 1u)) >> 16);  // RNE
}
__device__ __forceinline__ u32 cvtpk(float a, float b) {   // {lo:bf16(a), hi:bf16(b)}
    u32 d;
    asm("v_cvt_pk_bf16_f32 %0, %1, %2" : "=v"(d) : "v"(a), "v"(b));
    return d;
}
// v_permlane32_swap_b32: a[32..63] <-> b[0..31]
__device__ __forceinline__ void pswap(u32& a, u32& b) {
    asm("v_permlane32_swap_b32 %0, %1" : "+v"(a), "+v"(b));
}
__device__ __forceinline__ float max3f(float a, float b, float c) {
    float d;
    asm("v_max3_f32 %0, %1, %2, %3" : "=v"(d) : "v"(a), "v"(b), "v"(c));
    return d;
}
#define EXP2R(x) __builtin_amdgcn_exp2f(x)   // raw v_exp_f32 (|x| < 126 here)

// XCD-grouped work id from flat block id (requires gridDim.x % 8 == 0).
__device__ __forceinline__ int xcd_work(int bid, int nwg) {
    return (bid & 7) * (nwg >> 3) + (bid >> 3);
}

// global_load_lds, width 16 (literal size required)
#define GLL(srcp, dstp)                                                     \
    __builtin_amdgcn_global_load_lds(                                       \
        (const __attribute__((address_space(1))) u32*)(srcp),               \
        (__attribute__((address_space(3))) u32*)(dstp), 16, 0, 0)

// counted vmcnt waits (T4): never drain to 0 in the main loop
#define WAITCNT4() asm volatile("s_waitcnt vmcnt(4)" ::: "memory")
#define WAITCNT0() asm volatile("s_waitcnt vmcnt(0)" ::: "memory")
#define SCHEDB()   __builtin_amdgcn_sched_barrier(0)

// ---------------------------------------------------------------------------
// fp32 -> bf16 elementwise convert (grid-stride, 2048 blocks)
// ---------------------------------------------------------------------------
__global__ __launch_bounds__(256) void cvt_f32_bf16_kernel(
    const float4* __restrict__ in, ushort4* __restrict__ out, int n4)
{
    for (int i = blockIdx.x * 256 + threadIdx.x; i < n4; i += gridDim.x * 256) {
        float4 v = in[i];
        ushort4 o;
        o.x = f2b(v.x); o.y = f2b(v.y); o.z = f2b(v.z); o.w = f2b(v.w);
        out[i] = o;
    }
}

// ---------------------------------------------------------------------------
// Transpose + convert: in [R,Cc] fp32 -> out [Cc,R] bf16. 32x32 LDS tiles.
// ---------------------------------------------------------------------------
__global__ __launch_bounds__(256) void transpose_cvt_kernel(
    const float* __restrict__ in, u16* __restrict__ out, int R, int Cc)
{
    __shared__ u16 t[32][33];
    const int c0 = blockIdx.x * 32, r0 = blockIdx.y * 32;
    const int tx = threadIdx.x & 31, ty = threadIdx.x >> 5;  // 32 x 8
    #pragma unroll
    for (int i = 0; i < 32; i += 8)
        t[ty + i][tx] = f2b(in[(size_t)(r0 + ty + i) * Cc + c0 + tx]);
    __syncthreads();
    #pragma unroll
    for (int i = 0; i < 32; i += 8)
        out[(size_t)(c0 + ty + i) * R + r0 + tx] = t[tx][ty + i];
}

// ---------------------------------------------------------------------------
// QKV GEMM v6 - 8-phase-style schedule (m201 re-derivation at BK=32):
// 256x256 tile, 512 thr = 8 waves (2M x 4N), wave tile 128x64 (acc[8][4]).
// 3 full K-tile LDS buffers (96 KB, 1 block/CU): tile t reads buf[t%3];
// stage(t+2) -> buf[(t+2)%3] issued 2 GLL per phase (A in ph0, B in ph1).
// Counted vmcnt(4) at tile start (stage(t) landed, stage(t+1) in flight).
// Per phase: {GLL || ds_read frags || barrier -> setprio(1) 16 MFMA} x2.
// T2 swizzle: chunk ^= (row>>1)&3, both sides (GLL source preswizzled +
// swizzled ds_read) -> 2-way banks (free). B-frags held across both phases.
// Output: Q/K cols -> qkvb rows; V cols (>=2048) -> vT[b][c][t] transposed.
// ---------------------------------------------------------------------------
__global__ __launch_bounds__(512, 2) void gemm_qkv8_kernel(
    const u16* __restrict__ A, const u16* __restrict__ BT,
    const float* __restrict__ bias,
    u16* __restrict__ outb, u16* __restrict__ vTout,
    int N, int K, int nx)
{
    __shared__ u16 Al[3][256 * 32];   // 16KB per buffer
    __shared__ u16 Bl[3][256 * 32];

    const int tid = threadIdx.x;
    const int workid = xcd_work(blockIdx.x, gridDim.x);
    const int brow = (workid / nx) * 256;
    const int bcol = (workid % nx) * 256;
    const int w  = tid >> 6;          // wave 0..7
    const int wm = w >> 2, wn = w & 3;
    const int l  = tid & 63;
    const int lr = l & 15;
    const int g  = l >> 4;            // k-chunk 0..3
    const int rk = ((g ^ ((lr >> 1) & 3)) << 3);   // swizzled read chunk (u16)

    // staging: thread covers row j*128 + w*16 + (l>>2), source chunk swizzled
    const int srow = l >> 2;
    const int schk = ((l & 3) ^ ((l >> 3) & 3)) << 3;

    f32x4 acc[8][4];
    #pragma unroll
    for (int m = 0; m < 8; ++m)
        #pragma unroll
        for (int n = 0; n < 4; ++n) acc[m][n] = (f32x4){0.f, 0.f, 0.f, 0.f};

    // 2 GLL per thread per call (rows j*128.. covering 256 rows x 32 k)
    #define STG_A(k0, bufi)                                                    \
        do {                                                                   \
            GLL(&A[(size_t)(brow +       w * 16 + srow) * K + (k0) + schk],    \
                &Al[bufi][(w * 16) * 32]);                                     \
            GLL(&A[(size_t)(brow + 128 + w * 16 + srow) * K + (k0) + schk],    \
                &Al[bufi][(128 + w * 16) * 32]);                               \
        } while (0)
    #define STG_B(k0, bufi)                                                    \
        do {                                                                   \
            GLL(&BT[(size_t)(bcol +       w * 16 + srow) * K + (k0) + schk],   \
                &Bl[bufi][(w * 16) * 32]);                                     \
            GLL(&BT[(size_t)(bcol + 128 + w * 16 + srow) * K + (k0) + schk],   \
                &Bl[bufi][(128 + w * 16) * 32]);                               \
        } while (0)

    const int T = K >> 5;   // 32 K-tiles
    STG_A(0, 0);  STG_B(0, 0);
    STG_A(32, 1); STG_B(32, 1);

    for (int t = 0; t < T; ++t) {
        const int cur = t % 3;
        const int nxt = (t + 2) % 3;
        const int k0n = (t + 2) << 5;
        const u16* Ac = Al[cur];
        const u16* Bc = Bl[cur];

        // ---- phase 0: stage A(t+2) | read b[4], a0[4] | MFMA o=0 ----
        if (t < T - 1) WAITCNT4();   // stage(t) landed; stage(t+1) in flight
        else           WAITCNT0();
        __builtin_amdgcn_s_barrier();   // all waves: buf[cur] ready, buf[nxt] free
        SCHEDB();
        if (t + 2 < T) STG_A(k0n, nxt);

        bf16x8 bfr[4], afr[4];
        #pragma unroll
        for (int n = 0; n < 4; ++n)
            bfr[n] = *(const bf16x8*)&Bc[(wn * 64 + n * 16 + lr) * 32 + rk];
        #pragma unroll
        for (int m = 0; m < 4; ++m)
            afr[m] = *(const bf16x8*)&Ac[(wm * 128 + m * 16 + lr) * 32 + rk];

        __builtin_amdgcn_s_setprio(1);
        #pragma unroll
        for (int m = 0; m < 4; ++m)
            #pragma unroll
            for (int n = 0; n < 4; ++n)
                acc[m][n] = __builtin_amdgcn_mfma_f32_16x16x32_bf16(
                    afr[m], bfr[n], acc[m][n], 0, 0, 0);
        __builtin_amdgcn_s_setprio(0);
        __builtin_amdgcn_s_barrier();
        SCHEDB();

        // ---- phase 1: stage B(t+2) | read a1[4] | MFMA o=1 ----
        if (t + 2 < T) STG_B(k0n, nxt);
        #pragma unroll
        for (int m = 0; m < 4; ++m)
            afr[m] = *(const bf16x8*)&Ac[(wm * 128 + 64 + m * 16 + lr) * 32 + rk];

        __builtin_amdgcn_s_setprio(1);
        #pragma unroll
        for (int m = 0; m < 4; ++m)
            #pragma unroll
            for (int n = 0; n < 4; ++n)
                acc[4 + m][n] = __builtin_amdgcn_mfma_f32_16x16x32_bf16(
                    afr[m], bfr[n], acc[4 + m][n], 0, 0, 0);
        __builtin_amdgcn_s_setprio(0);
        __builtin_amdgcn_s_barrier();
        SCHEDB();
    }
    #undef STG_A
    #undef STG_B

    // Epilogue. C/D: col = lane&15, row = (lane>>4)*4 + reg.
    const int orow0 = brow + wm * 128 + (g << 2);
    const int ocol0 = bcol + wn * 64 + lr;
    if (bcol >= 2048) {
        // V section -> vT[b][c][t]; 4 acc regs = 4 consecutive t
        #pragma unroll
        for (int n = 0; n < 4; ++n) {
            const int c = ocol0 + n * 16 - 2048;
            const float bv = bias[ocol0 + n * 16];
            #pragma unroll
            for (int m = 0; m < 8; ++m) {
                const int row0 = orow0 + m * 16;
                const int bb = row0 >> 11, t0 = row0 & 2047;
                ushort4 pk;
                pk.x = f2b(acc[m][n][0] + bv);
                pk.y = f2b(acc[m][n][1] + bv);
                pk.z = f2b(acc[m][n][2] + bv);
                pk.w = f2b(acc[m][n][3] + bv);
                *(ushort4*)&vTout[((size_t)bb * Cn + c) * Tn + t0] = pk;
            }
        }
    } else {
        #pragma unroll
        for (int n = 0; n < 4; ++n) {
            const int col = ocol0 + n * 16;
            const float bv = bias[col];
            #pragma unroll
            for (int m = 0; m < 8; ++m) {
                #pragma unroll
                for (int r = 0; r < 4; ++r) {
                    const int row = orow0 + m * 16 + r;
                    outb[(size_t)row * N + col] = f2b(acc[m][n][r] + bv);
                }
            }
        }
    }
}

// ---------------------------------------------------------------------------
// Proj GEMM (square, R10/R12-verified): 128x128, BK=32, 4 waves, 3 buffers,
// counted vmcnt(4). f32 out. Grid 8x64 = 512 (2 blocks/CU).
// ---------------------------------------------------------------------------
__global__ __launch_bounds__(256) void gemm_proj_kernel(
    const u16* __restrict__ A, const u16* __restrict__ BT,
    const float* __restrict__ bias, float* __restrict__ outf,
    int N, int K, int nx)
{
    __shared__ u16 Al[3][128 * 32];
    __shared__ u16 Bl[3][128 * 32];

    const int tid = threadIdx.x;
    const int workid = xcd_work(blockIdx.x, gridDim.x);
    const int brow = (workid / nx) * 128;
    const int bcol = (workid % nx) * 128;
    const int w  = tid >> 6;
    const int wr = w >> 1, wc = w & 1;
    const int l  = tid & 63;
    const int lr = l & 15;
    const int lk = (l >> 4) << 3;

    const int r0s = tid >> 2,            c0s = (tid & 3) << 3;
    const int r1s = (256 + tid) >> 2;
    const int d0s = (tid & 192) * 8;
    const int d1s = (256 + (tid & 192)) * 8;

    f32x4 acc[4][4];
    #pragma unroll
    for (int m = 0; m < 4; ++m)
        #pragma unroll
        for (int n = 0; n < 4; ++n) acc[m][n] = (f32x4){0.f, 0.f, 0.f, 0.f};

    #define STAGE_P(k0, bufi)                                                \
        do {                                                                 \
            GLL(&A [(size_t)(brow + r0s) * K + (k0) + c0s], &Al[bufi][d0s]); \
            GLL(&BT[(size_t)(bcol + r0s) * K + (k0) + c0s], &Bl[bufi][d0s]); \
            GLL(&A [(size_t)(brow + r1s) * K + (k0) + c0s], &Al[bufi][d1s]); \
            GLL(&BT[(size_t)(bcol + r1s) * K + (k0) + c0s], &Bl[bufi][d1s]); \
        } while (0)

    const int T = K >> 5;
    STAGE_P(0, 0);
    STAGE_P(32, 1);

    int cur = 0;
    for (int t = 0; t < T; ++t) {
        if (t < T - 1) WAITCNT4();
        else           WAITCNT0();
        __builtin_amdgcn_s_barrier();

        if (t + 2 < T) {
            const int nb = cur + 2 >= 3 ? cur - 1 : cur + 2;
            STAGE_P((t + 2) << 5, nb);
        }

        bf16x8 a[4], b[4];
        #pragma unroll
        for (int m = 0; m < 4; ++m)
            a[m] = *(const bf16x8*)&Al[cur][(wr * 64 + m * 16 + lr) * 32 + lk];
        #pragma unroll
        for (int n = 0; n < 4; ++n)
            b[n] = *(const bf16x8*)&Bl[cur][(wc * 64 + n * 16 + lr) * 32 + lk];

        __builtin_amdgcn_s_setprio(1);
        #pragma unroll
        for (int m = 0; m < 4; ++m)
            #pragma unroll
            for (int n = 0; n < 4; ++n)
                acc[m][n] = __builtin_amdgcn_mfma_f32_16x16x32_bf16(
                    a[m], b[n], acc[m][n], 0, 0, 0);
        __builtin_amdgcn_s_setprio(0);

        cur = cur == 2 ? 0 : cur + 1;
    }
    #undef STAGE_P

    const int orow0 = brow + wr * 64 + ((l >> 4) << 2);
    const int ocol0 = bcol + wc * 64 + lr;
    #pragma unroll
    for (int n = 0; n < 4; ++n) {
        const int col = ocol0 + n * 16;
        const float bv = bias[col];
        #pragma unroll
        for (int m = 0; m < 4; ++m) {
            #pragma unroll
            for (int r = 0; r < 4; ++r) {
                const int row = orow0 + m * 16 + r;
                outf[(size_t)row * N + col] = acc[m][n][r] + bv;
            }
        }
    }
}

// ---------------------------------------------------------------------------
// MFMA flash attention v8 (causal) - unchanged from round 12 (verified).
// ---------------------------------------------------------------------------
__global__ __launch_bounds__(256, 2) void attn_mfma8_kernel(
    const u16* __restrict__ qkvb, const u16* __restrict__ vT,
    u16* __restrict__ yb)
{
    __shared__ u16 Kb[3][64 * 64];   // [k-row][d-chunk swizzled]
    __shared__ u16 Vb[3][64 * 64];   // [d-row][k-chunk swizzled]

    const int tid = threadIdx.x;
    const int w   = tid >> 6;        // wave 0..3
    const int l   = tid & 63;
    const int q31 = l & 31;          // q (QK^T B-col) / d (PV B-col)
    const int hi  = l >> 5;
    const int work = xcd_work(blockIdx.x, 512);
    const int pr  = work & 7;        // pair index 0..7
    const int bh  = work >> 3;       // 8 bh per XCD
    const int b   = bh >> 4, h = bh & 15;

    const float S2 = 0.18033688f;    // 0.125 * log2(e)

    const u16* Kg = qkvb + (size_t)(b * Tn) * (3 * Cn) + Cn + h * HDn;
    const u16* Vg = vT + (size_t)bh * HDn * Tn;

    const int srow = l >> 3;                   // staging row 0..7
    const int schk = ((l & 7) ^ srow) << 3;    // swizzled source chunk (u16)
    const int rloc = w * 16;                   // wave's staging row slice
    const int rsw8 = q31 & 7;                  // read-side XOR key (chunk idx)

    #define STAGE_A(kt, bufi)                                                  \
        do {                                                                   \
            _Pragma("unroll")                                                  \
            for (int jc = 0; jc < 2; ++jc) {                                   \
                const int rr = rloc + jc * 8;                                  \
                GLL(Kg + (size_t)((kt) * 64 + rr + srow) * (3 * Cn) + schk,    \
                    &Kb[bufi][rr * 64]);                                       \
                GLL(Vg + (size_t)(rr + srow) * Tn + (kt) * 64 + schk,          \
                    &Vb[bufi][rr * 64]);                                       \
            }                                                                  \
        } while (0)

    #pragma unroll 1
    for (int half = 0; half < 2; ++half) {
        const int qt = half ? (15 - pr) : pr;   // 128-row tile index
        const int ktmax = 2 * qt + 2;
        const int qrow0 = qt * 128 + w * 32;    // wave's first q row
        const int qglob = qrow0 + q31;          // this lane's q row

        // Q B-frags: qf[c] = Q[qglob][c*16 + hi*8 .. +7]
        const u16* Qp = qkvb + (size_t)(b * Tn + qglob) * (3 * Cn)
                        + h * HDn + hi * 8;
        bf16x8 qf[4];
        #pragma unroll
        for (int c = 0; c < 4; ++c) qf[c] = *(const bf16x8*)(Qp + c * 16);

        f32x16 O0, O1;
        #pragma unroll
        for (int r = 0; r < 16; ++r) { O0[r] = 0.f; O1[r] = 0.f; }
        float m = -INFINITY, ls = 0.f;

        STAGE_A(0, 0);
        STAGE_A(1, 1);

        int cur = 0;
        for (int kt = 0; kt < ktmax; ++kt) {
            if (kt < ktmax - 1) WAITCNT4();
            else                WAITCNT0();
            __builtin_amdgcn_s_barrier();

            if (kt + 2 < ktmax) {
                const int nb = cur + 2 >= 3 ? cur - 1 : cur + 2;
                STAGE_A(kt + 2, nb);
            }
            const u16* Kc = Kb[cur];
            const u16* Vc = Vb[cur];

            if (kt * 64 <= qrow0 + 31) {   // wave has unmasked work
                // S^T = K Q^T : two 32x32 tiles (k 0..31, 32..63)
                f32x16 S0, S1;
                #pragma unroll
                for (int r = 0; r < 16; ++r) { S0[r] = 0.f; S1[r] = 0.f; }
                __builtin_amdgcn_s_setprio(1);
                #pragma unroll
                for (int c = 0; c < 4; ++c) {
                    const int co = ((2 * c + hi) ^ rsw8) << 3;
                    const bf16x8 k0 = *(const bf16x8*)&Kc[q31 * 64 + co];
                    const bf16x8 k1 = *(const bf16x8*)&Kc[(32 + q31) * 64 + co];
                    S0 = __builtin_amdgcn_mfma_f32_32x32x16_bf16(k0, qf[c], S0, 0, 0, 0);
                    S1 = __builtin_amdgcn_mfma_f32_32x32x16_bf16(k1, qf[c], S1, 0, 0, 0);
                }
                __builtin_amdgcn_s_setprio(0);

                // causal mask (diagonal-straddling steps only)
                if (kt * 64 + 63 > qrow0) {
                    #pragma unroll
                    for (int r = 0; r < 16; ++r) {
                        const int kl = kt * 64 + (r & 3) + 8 * (r >> 2) + 4 * hi;
                        if (kl > qglob)      S0[r] = -INFINITY;
                        if (kl + 32 > qglob) S1[r] = -INFINITY;
                    }
                }

                // row max: v_max3 tree (depth 4) + 1 cross-half shuffle
                float a0 = max3f(S0[0],  S0[1],  S0[2]);
                float a1 = max3f(S0[3],  S0[4],  S0[5]);
                float a2 = max3f(S0[6],  S0[7],  S0[8]);
                float a3 = max3f(S0[9],  S0[10], S0[11]);
                float a4 = max3f(S0[12], S0[13], S0[14]);
                float a5 = max3f(S0[15], S1[0],  S1[1]);
                float a6 = max3f(S1[2],  S1[3],  S1[4]);
                float a7 = max3f(S1[5],  S1[6],  S1[7]);
                float a8 = max3f(S1[8],  S1[9],  S1[10]);
                float a9 = max3f(S1[11], S1[12], S1[13]);
                float aA = fmaxf(S1[14], S1[15]);
                float b0 = max3f(a0, a1, a2);
                float b1 = max3f(a3, a4, a5);
                float b2 = max3f(a6, a7, a8);
                float b3 = fmaxf(a9, aA);
                float mt = fmaxf(fmaxf(b0, b1), fmaxf(b2, b3));
                mt = fmaxf(mt, __shfl_xor(mt, 32));

                // defer-max (first active step always triggers: m = -inf)
                float lscale = 1.f;
                if (__any(mt > m + 64.f)) {
                    const float mn = fmaxf(m, mt);
                    const float alpha = EXP2R((m - mn) * S2);
                    m = mn; lscale = alpha;
                    #pragma unroll
                    for (int r = 0; r < 16; ++r) {
                        const int qloc = (r & 3) + 8 * (r >> 2) + 4 * hi;
                        const float ar = __shfl(alpha, qloc);
                        O0[r] *= ar; O1[r] *= ar;
                    }
                }

                // P = exp2(S*S2 - m*S2) via fmaf + raw v_exp_f32
                const float nms2 = -m * S2;
                float lt0 = 0.f, lt1 = 0.f;
                u32 w0[8], w1[8];
                #pragma unroll
                for (int i = 0; i < 8; ++i) {
                    const float p0 = EXP2R(fmaf(S0[2 * i],     S2, nms2));
                    const float p1 = EXP2R(fmaf(S0[2 * i + 1], S2, nms2));
                    const float p2 = EXP2R(fmaf(S1[2 * i],     S2, nms2));
                    const float p3 = EXP2R(fmaf(S1[2 * i + 1], S2, nms2));
                    lt0 += (p0 + p1);
                    lt1 += (p2 + p3);
                    w0[i] = cvtpk(p0, p1);
                    w1[i] = cvtpk(p2, p3);
                }
                float lt = lt0 + lt1;
                lt += __shfl_xor(lt, 32);
                ls = ls * lscale + lt;

                // O += P @ V : assemble A-frags via permlane32_swap, B from Vs
                __builtin_amdgcn_s_setprio(1);
                #pragma unroll
                for (int t2 = 0; t2 < 2; ++t2) {
                    #pragma unroll
                    for (int c1 = 0; c1 < 2; ++c1) {
                        u32 a0w = t2 ? w1[4 * c1 + 0] : w0[4 * c1 + 0];
                        u32 b0w = t2 ? w1[4 * c1 + 2] : w0[4 * c1 + 2];
                        u32 a1w = t2 ? w1[4 * c1 + 1] : w0[4 * c1 + 1];
                        u32 b1w = t2 ? w1[4 * c1 + 3] : w0[4 * c1 + 3];
                        pswap(a0w, b0w);   // -> frag words 0 and 2
                        pswap(a1w, b1w);   // -> frag words 1 and 3
                        u32x4 fr; fr.x = a0w; fr.y = a1w; fr.z = b0w; fr.w = b1w;
                        const bf16x8 pf = __builtin_bit_cast(bf16x8, fr);
                        const int c = t2 * 2 + c1;
                        const int co = ((2 * c + hi) ^ rsw8) << 3;
                        const bf16x8 v0 = *(const bf16x8*)&Vc[q31 * 64 + co];
                        const bf16x8 v1 = *(const bf16x8*)&Vc[(32 + q31) * 64 + co];
                        O0 = __builtin_amdgcn_mfma_f32_32x32x16_bf16(pf, v0, O0, 0, 0, 0);
                        O1 = __builtin_amdgcn_mfma_f32_32x32x16_bf16(pf, v1, O1, 0, 0, 0);
                    }
                }
                __builtin_amdgcn_s_setprio(0);
            }

            cur = cur == 2 ? 0 : cur + 1;
        }

        // all waves done with LDS before next half's prologue restages
        __builtin_amdgcn_s_barrier();

        // epilogue: O row r -> q = qrow0 + (r&3)+8*(r>>2)+4*hi, col = d
        #pragma unroll
        for (int r = 0; r < 16; ++r) {
            const int qloc = (r & 3) + 8 * (r >> 2) + 4 * hi;
            const float inv = __builtin_amdgcn_rcpf(__shfl(ls, qloc));
            u16* yp = yb + (size_t)(b * Tn + qrow0 + qloc) * Cn + h * HDn + q31;
            yp[0]  = f2b(O0[r] * inv);
            yp[32] = f2b(O1[r] * inv);
        }
    }
    #undef STAGE_A
}

// ---------------------------------------------------------------------------
extern "C" void kernel_launch(void* const* d_in, const int* in_sizes, int n_in,
                              void* d_out, int out_size, void* d_ws, size_t ws_size,
                              hipStream_t stream)
{
    const float* x      = (const float*)d_in[0];
    const float* W_attn = (const float*)d_in[1];
    const float* b_attn = (const float*)d_in[2];
    const float* W_proj = (const float*)d_in[3];
    const float* b_proj = (const float*)d_in[4];
    float* out = (float*)d_out;

    // Workspace (bf16): xb | WaT | WpT | qkvb | yb | vT  (~108 MB)
    u16* xb   = (u16*)d_ws;
    u16* WaT  = xb   + (size_t)Mn * Cn;
    u16* WpT  = WaT  + (size_t)3 * Cn * Cn;
    u16* qkvb = WpT  + (size_t)Cn * Cn;
    u16* yb   = qkvb + (size_t)Mn * 3 * Cn;
    u16* vT   = yb   + (size_t)Mn * Cn;

    cvt_f32_bf16_kernel<<<2048, 256, 0, stream>>>(
        (const float4*)x, (ushort4*)xb, Mn * Cn / 4);

    transpose_cvt_kernel<<<dim3(3 * Cn / 32, Cn / 32), 256, 0, stream>>>(
        W_attn, WaT, Cn, 3 * Cn);
    transpose_cvt_kernel<<<dim3(Cn / 32, Cn / 32), 256, 0, stream>>>(
        W_proj, WpT, Cn, Cn);

    // qkv = x @ W_attn + b_attn; Q/K -> qkvb rows, V -> vT (fused transpose)
    // 256x256 tiles: grid 32 x 12 = 384 blocks (512 threads each)
    gemm_qkv8_kernel<<<32 * 12, 512, 0, stream>>>(
        xb, WaT, b_attn, qkvb, vT, 3 * Cn, Cn, 12);

    // causal MFMA attention -> yb (bf16); grid 512, XCD-grouped
    attn_mfma8_kernel<<<512, 256, 0, stream>>>(qkvb, vT, yb);

    // out = y @ W_proj + b_proj (f32 out); grid 512 (2 blocks/CU)
    gemm_proj_kernel<<<8 * 64, 256, 0, stream>>>(
        yb, WpT, b_proj, out, Cn, Cn, 8);
}

// Round 15
// 189.341 us; speedup vs baseline: 1.2304x; 1.0563x over previous
//
#include <hip/hip_runtime.h>
#include <math.h>

// Problem constants
#define Bn 4
#define Tn 2048
#define Cn 1024
#define Hn 16
#define HDn 64
#define Mn (Bn * Tn)  // 8192 tokens

typedef unsigned short u16;
typedef unsigned int u32;
typedef __attribute__((ext_vector_type(8))) short bf16x8;        // 8 bf16 = 4 VGPRs
typedef __attribute__((ext_vector_type(8))) unsigned short us8;  // 16B chunk
typedef __attribute__((ext_vector_type(4))) float f32x4;         // 16x16 MFMA acc
typedef __attribute__((ext_vector_type(16))) float f32x16;       // 32x32 MFMA acc
typedef __attribute__((ext_vector_type(4))) unsigned int u32x4;

__device__ __forceinline__ float b2f(u16 u) {
    return __uint_as_float(((u32)u) << 16);
}
__device__ __forceinline__ u16 f2b(float f) {
    u32 u = __float_as_uint(f);
    return (u16)((u + 0x7FFFu + ((u >> 16) & 1u)) >> 16);  // RNE
}
__device__ __forceinline__ u32 cvtpk(float a, float b) {   // {lo:bf16(a), hi:bf16(b)}
    u32 d;
    asm("v_cvt_pk_bf16_f32 %0, %1, %2" : "=v"(d) : "v"(a), "v"(b));
    return d;
}
// v_permlane32_swap_b32: a[32..63] <-> b[0..31]
__device__ __forceinline__ void pswap(u32& a, u32& b) {
    asm("v_permlane32_swap_b32 %0, %1" : "+v"(a), "+v"(b));
}
__device__ __forceinline__ float max3f(float a, float b, float c) {
    float d;
    asm("v_max3_f32 %0, %1, %2, %3" : "=v"(d) : "v"(a), "v"(b), "v"(c));
    return d;
}
#define EXP2R(x) __builtin_amdgcn_exp2f(x)   // raw v_exp_f32 (|x| < 126 here)

// XCD-grouped work id from flat block id (requires gridDim.x % 8 == 0).
__device__ __forceinline__ int xcd_work(int bid, int nwg) {
    return (bid & 7) * (nwg >> 3) + (bid >> 3);
}

// global_load_lds, width 16 (literal size required)
#define GLL(srcp, dstp)                                                     \
    __builtin_amdgcn_global_load_lds(                                       \
        (const __attribute__((address_space(1))) u32*)(srcp),               \
        (__attribute__((address_space(3))) u32*)(dstp), 16, 0, 0)

// counted vmcnt waits (T4): never drain to 0 in the main loop
#define WAITCNT6() asm volatile("s_waitcnt vmcnt(6)" ::: "memory")
#define WAITCNT4() asm volatile("s_waitcnt vmcnt(4)" ::: "memory")
#define WAITCNT0() asm volatile("s_waitcnt vmcnt(0)" ::: "memory")

// ---------------------------------------------------------------------------
// fp32 -> bf16 elementwise convert (grid-stride, 2048 blocks)
// ---------------------------------------------------------------------------
__global__ __launch_bounds__(256) void cvt_f32_bf16_kernel(
    const float4* __restrict__ in, ushort4* __restrict__ out, int n4)
{
    for (int i = blockIdx.x * 256 + threadIdx.x; i < n4; i += gridDim.x * 256) {
        float4 v = in[i];
        ushort4 o;
        o.x = f2b(v.x); o.y = f2b(v.y); o.z = f2b(v.z); o.w = f2b(v.w);
        out[i] = o;
    }
}

// ---------------------------------------------------------------------------
// Transpose + convert: in [R,Cc] fp32 -> out [Cc,R] bf16. 32x32 LDS tiles.
// ---------------------------------------------------------------------------
__global__ __launch_bounds__(256) void transpose_cvt_kernel(
    const float* __restrict__ in, u16* __restrict__ out, int R, int Cc)
{
    __shared__ u16 t[32][33];
    const int c0 = blockIdx.x * 32, r0 = blockIdx.y * 32;
    const int tx = threadIdx.x & 31, ty = threadIdx.x >> 5;  // 32 x 8
    #pragma unroll
    for (int i = 0; i < 32; i += 8)
        t[ty + i][tx] = f2b(in[(size_t)(r0 + ty + i) * Cc + c0 + tx]);
    __syncthreads();
    #pragma unroll
    for (int i = 0; i < 32; i += 8)
        out[(size_t)(c0 + ty + i) * R + r0 + tx] = t[tx][ty + i];
}

// ---------------------------------------------------------------------------
// QKV GEMM (R12-verified, 83.5us): 128x256 block, BK=32, 4 waves (2Mx2N),
// wave tile 64x128. Triple-buffered LDS, counted vmcnt(6), one s_barrier per
// K-step. Q/K cols -> qkvb rows; V cols (>=2048) -> vT[b][c][t] transposed.
// Grid 64x12 = 768 (3 exact CU rounds). No setprio (m190: hurts lockstep).
// ---------------------------------------------------------------------------
__global__ __launch_bounds__(256, 2) void gemm_qkv_kernel(
    const u16* __restrict__ A, const u16* __restrict__ BT,
    const float* __restrict__ bias,
    u16* __restrict__ outb, u16* __restrict__ vTout,
    int N, int K, int nx)
{
    __shared__ u16 Al[3][128 * 32];
    __shared__ u16 Bl[3][256 * 32];

    const int tid = threadIdx.x;
    const int workid = xcd_work(blockIdx.x, gridDim.x);
    const int brow = (workid / nx) * 128;
    const int bcol = (workid % nx) * 256;
    const int w  = tid >> 6;
    const int wr = w >> 1, wc = w & 1;
    const int l  = tid & 63;
    const int lr = l & 15;
    const int lk = (l >> 4) << 3;

    const int sr = l >> 2;
    const int sc = (l & 3) << 3;

    f32x4 acc[4][8];
    #pragma unroll
    for (int m = 0; m < 4; ++m)
        #pragma unroll
        for (int n = 0; n < 8; ++n) acc[m][n] = (f32x4){0.f, 0.f, 0.f, 0.f};

    #define STAGE_G(k0, bufi)                                                   \
        do {                                                                    \
            GLL(&A [(size_t)(brow + 32 * w +      sr) * K + (k0) + sc],         \
                &Al[bufi][(32 * w) * 32]);                                      \
            GLL(&A [(size_t)(brow + 32 * w + 16 + sr) * K + (k0) + sc],         \
                &Al[bufi][(32 * w + 16) * 32]);                                 \
            GLL(&BT[(size_t)(bcol + 64 * w +      sr) * K + (k0) + sc],         \
                &Bl[bufi][(64 * w) * 32]);                                      \
            GLL(&BT[(size_t)(bcol + 64 * w + 16 + sr) * K + (k0) + sc],         \
                &Bl[bufi][(64 * w + 16) * 32]);                                 \
            GLL(&BT[(size_t)(bcol + 64 * w + 32 + sr) * K + (k0) + sc],         \
                &Bl[bufi][(64 * w + 32) * 32]);                                 \
            GLL(&BT[(size_t)(bcol + 64 * w + 48 + sr) * K + (k0) + sc],         \
                &Bl[bufi][(64 * w + 48) * 32]);                                 \
        } while (0)

    const int T = K >> 5;
    STAGE_G(0, 0);
    STAGE_G(32, 1);

    int cur = 0;
    for (int t = 0; t < T; ++t) {
        if (t < T - 1) WAITCNT6();
        else           WAITCNT0();
        __builtin_amdgcn_s_barrier();

        if (t + 2 < T) {
            const int nb = cur + 2 >= 3 ? cur - 1 : cur + 2;
            STAGE_G((t + 2) << 5, nb);
        }

        bf16x8 a[4], b[8];
        #pragma unroll
        for (int m = 0; m < 4; ++m)
            a[m] = *(const bf16x8*)&Al[cur][(wr * 64 + m * 16 + lr) * 32 + lk];
        #pragma unroll
        for (int n = 0; n < 8; ++n)
            b[n] = *(const bf16x8*)&Bl[cur][(wc * 128 + n * 16 + lr) * 32 + lk];

        #pragma unroll
        for (int m = 0; m < 4; ++m)
            #pragma unroll
            for (int n = 0; n < 8; ++n)
                acc[m][n] = __builtin_amdgcn_mfma_f32_16x16x32_bf16(
                    a[m], b[n], acc[m][n], 0, 0, 0);

        cur = cur == 2 ? 0 : cur + 1;
    }
    #undef STAGE_G

    // Epilogue. C/D layout: col = lane&15, row = (lane>>4)*4 + reg.
    const int orow0 = brow + wr * 64 + ((l >> 4) << 2);
    const int ocol0 = bcol + wc * 128 + lr;
    if (bcol >= 2048) {
        #pragma unroll
        for (int n = 0; n < 8; ++n) {
            const int c = ocol0 + n * 16 - 2048;
            const float bv = bias[ocol0 + n * 16];
            #pragma unroll
            for (int m = 0; m < 4; ++m) {
                const int row0 = orow0 + m * 16;
                const int bb = row0 >> 11, t0 = row0 & 2047;
                ushort4 pk;
                pk.x = f2b(acc[m][n][0] + bv);
                pk.y = f2b(acc[m][n][1] + bv);
                pk.z = f2b(acc[m][n][2] + bv);
                pk.w = f2b(acc[m][n][3] + bv);
                *(ushort4*)&vTout[((size_t)bb * Cn + c) * Tn + t0] = pk;
            }
        }
    } else {
        #pragma unroll
        for (int n = 0; n < 8; ++n) {
            const int col = ocol0 + n * 16;
            const float bv = bias[col];
            #pragma unroll
            for (int m = 0; m < 4; ++m) {
                #pragma unroll
                for (int r = 0; r < 4; ++r) {
                    const int row = orow0 + m * 16 + r;
                    outb[(size_t)row * N + col] = f2b(acc[m][n][r] + bv);
                }
            }
        }
    }
}

// ---------------------------------------------------------------------------
// Proj GEMM (R12-verified): 128x128, BK=32, 4 waves, 3 buffers, counted
// vmcnt(4). f32 out. Grid 8x64 = 512 (2 blocks/CU). No setprio.
// ---------------------------------------------------------------------------
__global__ __launch_bounds__(256) void gemm_proj_kernel(
    const u16* __restrict__ A, const u16* __restrict__ BT,
    const float* __restrict__ bias, float* __restrict__ outf,
    int N, int K, int nx)
{
    __shared__ u16 Al[3][128 * 32];
    __shared__ u16 Bl[3][128 * 32];

    const int tid = threadIdx.x;
    const int workid = xcd_work(blockIdx.x, gridDim.x);
    const int brow = (workid / nx) * 128;
    const int bcol = (workid % nx) * 128;
    const int w  = tid >> 6;
    const int wr = w >> 1, wc = w & 1;
    const int l  = tid & 63;
    const int lr = l & 15;
    const int lk = (l >> 4) << 3;

    const int r0s = tid >> 2,            c0s = (tid & 3) << 3;
    const int r1s = (256 + tid) >> 2;
    const int d0s = (tid & 192) * 8;
    const int d1s = (256 + (tid & 192)) * 8;

    f32x4 acc[4][4];
    #pragma unroll
    for (int m = 0; m < 4; ++m)
        #pragma unroll
        for (int n = 0; n < 4; ++n) acc[m][n] = (f32x4){0.f, 0.f, 0.f, 0.f};

    #define STAGE_P(k0, bufi)                                                \
        do {                                                                 \
            GLL(&A [(size_t)(brow + r0s) * K + (k0) + c0s], &Al[bufi][d0s]); \
            GLL(&BT[(size_t)(bcol + r0s) * K + (k0) + c0s], &Bl[bufi][d0s]); \
            GLL(&A [(size_t)(brow + r1s) * K + (k0) + c0s], &Al[bufi][d1s]); \
            GLL(&BT[(size_t)(bcol + r1s) * K + (k0) + c0s], &Bl[bufi][d1s]); \
        } while (0)

    const int T = K >> 5;
    STAGE_P(0, 0);
    STAGE_P(32, 1);

    int cur = 0;
    for (int t = 0; t < T; ++t) {
        if (t < T - 1) WAITCNT4();
        else           WAITCNT0();
        __builtin_amdgcn_s_barrier();

        if (t + 2 < T) {
            const int nb = cur + 2 >= 3 ? cur - 1 : cur + 2;
            STAGE_P((t + 2) << 5, nb);
        }

        bf16x8 a[4], b[4];
        #pragma unroll
        for (int m = 0; m < 4; ++m)
            a[m] = *(const bf16x8*)&Al[cur][(wr * 64 + m * 16 + lr) * 32 + lk];
        #pragma unroll
        for (int n = 0; n < 4; ++n)
            b[n] = *(const bf16x8*)&Bl[cur][(wc * 64 + n * 16 + lr) * 32 + lk];

        #pragma unroll
        for (int m = 0; m < 4; ++m)
            #pragma unroll
            for (int n = 0; n < 4; ++n)
                acc[m][n] = __builtin_amdgcn_mfma_f32_16x16x32_bf16(
                    a[m], b[n], acc[m][n], 0, 0, 0);

        cur = cur == 2 ? 0 : cur + 1;
    }
    #undef STAGE_P

    const int orow0 = brow + wr * 64 + ((l >> 4) << 2);
    const int ocol0 = bcol + wc * 64 + lr;
    #pragma unroll
    for (int n = 0; n < 4; ++n) {
        const int col = ocol0 + n * 16;
        const float bv = bias[col];
        #pragma unroll
        for (int m = 0; m < 4; ++m) {
            #pragma unroll
            for (int r = 0; r < 4; ++r) {
                const int row = orow0 + m * 16 + r;
                outf[(size_t)row * N + col] = acc[m][n][r] + bv;
            }
        }
    }
}

// ---------------------------------------------------------------------------
// MFMA flash attention v9 (causal) - v8 math, ONE 128-row q-tile per block.
// Grid 16 qt x 64 bh = 1024, XCD-grouped (bh = work>>4: 8 heads/XCD for K/V
// L2 residency; qt spread within XCD averages the causal imbalance).
// 48KB LDS + launch_bounds(256,3) -> 3 blocks/CU (3 waves/SIMD, +50% latency
// hiding vs the paired 2-blocks/CU variant).
// ---------------------------------------------------------------------------
__global__ __launch_bounds__(256, 3) void attn_mfma9_kernel(
    const u16* __restrict__ qkvb, const u16* __restrict__ vT,
    u16* __restrict__ yb)
{
    __shared__ u16 Kb[3][64 * 64];   // [k-row][d-chunk swizzled]
    __shared__ u16 Vb[3][64 * 64];   // [d-row][k-chunk swizzled]

    const int tid = threadIdx.x;
    const int w   = tid >> 6;        // wave 0..3
    const int l   = tid & 63;
    const int q31 = l & 31;          // q (QK^T B-col) / d (PV B-col)
    const int hi  = l >> 5;
    const int work = xcd_work(blockIdx.x, 1024);
    const int qt  = work & 15;       // 128-row tile index
    const int bh  = work >> 4;       // 8 bh per XCD
    const int b   = bh >> 4, h = bh & 15;

    const float S2 = 0.18033688f;    // 0.125 * log2(e)

    const u16* Kg = qkvb + (size_t)(b * Tn) * (3 * Cn) + Cn + h * HDn;
    const u16* Vg = vT + (size_t)bh * HDn * Tn;

    const int srow = l >> 3;                   // staging row 0..7
    const int schk = ((l & 7) ^ srow) << 3;    // swizzled source chunk (u16)
    const int rloc = w * 16;                   // wave's staging row slice
    const int rsw8 = q31 & 7;                  // read-side XOR key (chunk idx)

    #define STAGE_A(kt, bufi)                                                  \
        do {                                                                   \
            _Pragma("unroll")                                                  \
            for (int jc = 0; jc < 2; ++jc) {                                   \
                const int rr = rloc + jc * 8;                                  \
                GLL(Kg + (size_t)((kt) * 64 + rr + srow) * (3 * Cn) + schk,    \
                    &Kb[bufi][rr * 64]);                                       \
                GLL(Vg + (size_t)(rr + srow) * Tn + (kt) * 64 + schk,          \
                    &Vb[bufi][rr * 64]);                                       \
            }                                                                  \
        } while (0)

    const int ktmax = 2 * qt + 2;
    const int qrow0 = qt * 128 + w * 32;    // wave's first q row
    const int qglob = qrow0 + q31;          // this lane's q row

    // Q B-frags: qf[c] = Q[qglob][c*16 + hi*8 .. +7]
    const u16* Qp = qkvb + (size_t)(b * Tn + qglob) * (3 * Cn)
                    + h * HDn + hi * 8;
    bf16x8 qf[4];
    #pragma unroll
    for (int c = 0; c < 4; ++c) qf[c] = *(const bf16x8*)(Qp + c * 16);

    f32x16 O0, O1;
    #pragma unroll
    for (int r = 0; r < 16; ++r) { O0[r] = 0.f; O1[r] = 0.f; }
    float m = -INFINITY, ls = 0.f;

    STAGE_A(0, 0);
    STAGE_A(1, 1);

    int cur = 0;
    for (int kt = 0; kt < ktmax; ++kt) {
        if (kt < ktmax - 1) WAITCNT4();
        else                WAITCNT0();
        __builtin_amdgcn_s_barrier();

        if (kt + 2 < ktmax) {
            const int nb = cur + 2 >= 3 ? cur - 1 : cur + 2;
            STAGE_A(kt + 2, nb);
        }
        const u16* Kc = Kb[cur];
        const u16* Vc = Vb[cur];

        if (kt * 64 <= qrow0 + 31) {   // wave has unmasked work
            // S^T = K Q^T : two 32x32 tiles (k 0..31, 32..63)
            f32x16 S0, S1;
            #pragma unroll
            for (int r = 0; r < 16; ++r) { S0[r] = 0.f; S1[r] = 0.f; }
            __builtin_amdgcn_s_setprio(1);
            #pragma unroll
            for (int c = 0; c < 4; ++c) {
                const int co = ((2 * c + hi) ^ rsw8) << 3;
                const bf16x8 k0 = *(const bf16x8*)&Kc[q31 * 64 + co];
                const bf16x8 k1 = *(const bf16x8*)&Kc[(32 + q31) * 64 + co];
                S0 = __builtin_amdgcn_mfma_f32_32x32x16_bf16(k0, qf[c], S0, 0, 0, 0);
                S1 = __builtin_amdgcn_mfma_f32_32x32x16_bf16(k1, qf[c], S1, 0, 0, 0);
            }
            __builtin_amdgcn_s_setprio(0);

            // causal mask (diagonal-straddling steps only)
            if (kt * 64 + 63 > qrow0) {
                #pragma unroll
                for (int r = 0; r < 16; ++r) {
                    const int kl = kt * 64 + (r & 3) + 8 * (r >> 2) + 4 * hi;
                    if (kl > qglob)      S0[r] = -INFINITY;
                    if (kl + 32 > qglob) S1[r] = -INFINITY;
                }
            }

            // row max: v_max3 tree (depth 4) + 1 cross-half shuffle
            float a0 = max3f(S0[0],  S0[1],  S0[2]);
            float a1 = max3f(S0[3],  S0[4],  S0[5]);
            float a2 = max3f(S0[6],  S0[7],  S0[8]);
            float a3 = max3f(S0[9],  S0[10], S0[11]);
            float a4 = max3f(S0[12], S0[13], S0[14]);
            float a5 = max3f(S0[15], S1[0],  S1[1]);
            float a6 = max3f(S1[2],  S1[3],  S1[4]);
            float a7 = max3f(S1[5],  S1[6],  S1[7]);
            float a8 = max3f(S1[8],  S1[9],  S1[10]);
            float a9 = max3f(S1[11], S1[12], S1[13]);
            float aA = fmaxf(S1[14], S1[15]);
            float b0 = max3f(a0, a1, a2);
            float b1 = max3f(a3, a4, a5);
            float b2 = max3f(a6, a7, a8);
            float b3 = fmaxf(a9, aA);
            float mt = fmaxf(fmaxf(b0, b1), fmaxf(b2, b3));
            mt = fmaxf(mt, __shfl_xor(mt, 32));

            // defer-max (first active step always triggers: m = -inf)
            float lscale = 1.f;
            if (__any(mt > m + 64.f)) {
                const float mn = fmaxf(m, mt);
                const float alpha = EXP2R((m - mn) * S2);
                m = mn; lscale = alpha;
                #pragma unroll
                for (int r = 0; r < 16; ++r) {
                    const int qloc = (r & 3) + 8 * (r >> 2) + 4 * hi;
                    const float ar = __shfl(alpha, qloc);
                    O0[r] *= ar; O1[r] *= ar;
                }
            }

            // P = exp2(S*S2 - m*S2) via fmaf + raw v_exp_f32
            const float nms2 = -m * S2;
            float lt0 = 0.f, lt1 = 0.f;
            u32 w0[8], w1[8];
            #pragma unroll
            for (int i = 0; i < 8; ++i) {
                const float p0 = EXP2R(fmaf(S0[2 * i],     S2, nms2));
                const float p1 = EXP2R(fmaf(S0[2 * i + 1], S2, nms2));
                const float p2 = EXP2R(fmaf(S1[2 * i],     S2, nms2));
                const float p3 = EXP2R(fmaf(S1[2 * i + 1], S2, nms2));
                lt0 += (p0 + p1);
                lt1 += (p2 + p3);
                w0[i] = cvtpk(p0, p1);
                w1[i] = cvtpk(p2, p3);
            }
            float lt = lt0 + lt1;
            lt += __shfl_xor(lt, 32);
            ls = ls * lscale + lt;

            // O += P @ V : assemble A-frags via permlane32_swap, B from Vs
            __builtin_amdgcn_s_setprio(1);
            #pragma unroll
            for (int t2 = 0; t2 < 2; ++t2) {
                #pragma unroll
                for (int c1 = 0; c1 < 2; ++c1) {
                    u32 a0w = t2 ? w1[4 * c1 + 0] : w0[4 * c1 + 0];
                    u32 b0w = t2 ? w1[4 * c1 + 2] : w0[4 * c1 + 2];
                    u32 a1w = t2 ? w1[4 * c1 + 1] : w0[4 * c1 + 1];
                    u32 b1w = t2 ? w1[4 * c1 + 3] : w0[4 * c1 + 3];
                    pswap(a0w, b0w);   // -> frag words 0 and 2
                    pswap(a1w, b1w);   // -> frag words 1 and 3
                    u32x4 fr; fr.x = a0w; fr.y = a1w; fr.z = b0w; fr.w = b1w;
                    const bf16x8 pf = __builtin_bit_cast(bf16x8, fr);
                    const int c = t2 * 2 + c1;
                    const int co = ((2 * c + hi) ^ rsw8) << 3;
                    const bf16x8 v0 = *(const bf16x8*)&Vc[q31 * 64 + co];
                    const bf16x8 v1 = *(const bf16x8*)&Vc[(32 + q31) * 64 + co];
                    O0 = __builtin_amdgcn_mfma_f32_32x32x16_bf16(pf, v0, O0, 0, 0, 0);
                    O1 = __builtin_amdgcn_mfma_f32_32x32x16_bf16(pf, v1, O1, 0, 0, 0);
                }
            }
            __builtin_amdgcn_s_setprio(0);
        }

        cur = cur == 2 ? 0 : cur + 1;
    }

    // epilogue: O row r -> q = qrow0 + (r&3)+8*(r>>2)+4*hi, col = d
    #pragma unroll
    for (int r = 0; r < 16; ++r) {
        const int qloc = (r & 3) + 8 * (r >> 2) + 4 * hi;
        const float inv = __builtin_amdgcn_rcpf(__shfl(ls, qloc));
        u16* yp = yb + (size_t)(b * Tn + qrow0 + qloc) * Cn + h * HDn + q31;
        yp[0]  = f2b(O0[r] * inv);
        yp[32] = f2b(O1[r] * inv);
    }
    #undef STAGE_A
}

// ---------------------------------------------------------------------------
extern "C" void kernel_launch(void* const* d_in, const int* in_sizes, int n_in,
                              void* d_out, int out_size, void* d_ws, size_t ws_size,
                              hipStream_t stream)
{
    const float* x      = (const float*)d_in[0];
    const float* W_attn = (const float*)d_in[1];
    const float* b_attn = (const float*)d_in[2];
    const float* W_proj = (const float*)d_in[3];
    const float* b_proj = (const float*)d_in[4];
    float* out = (float*)d_out;

    // Workspace (bf16): xb | WaT | WpT | qkvb | yb | vT  (~108 MB)
    u16* xb   = (u16*)d_ws;
    u16* WaT  = xb   + (size_t)Mn * Cn;
    u16* WpT  = WaT  + (size_t)3 * Cn * Cn;
    u16* qkvb = WpT  + (size_t)Cn * Cn;
    u16* yb   = qkvb + (size_t)Mn * 3 * Cn;
    u16* vT   = yb   + (size_t)Mn * Cn;

    cvt_f32_bf16_kernel<<<2048, 256, 0, stream>>>(
        (const float4*)x, (ushort4*)xb, Mn * Cn / 4);

    transpose_cvt_kernel<<<dim3(3 * Cn / 32, Cn / 32), 256, 0, stream>>>(
        W_attn, WaT, Cn, 3 * Cn);
    transpose_cvt_kernel<<<dim3(Cn / 32, Cn / 32), 256, 0, stream>>>(
        W_proj, WpT, Cn, Cn);

    // qkv = x @ W_attn + b_attn; Q/K -> qkvb rows, V -> vT (fused transpose)
    gemm_qkv_kernel<<<64 * 12, 256, 0, stream>>>(
        xb, WaT, b_attn, qkvb, vT, 3 * Cn, Cn, 12);

    // causal MFMA attention -> yb (bf16); grid 1024 (3 blocks/CU), XCD-grouped
    attn_mfma9_kernel<<<1024, 256, 0, stream>>>(qkvb, vT, yb);

    // out = y @ W_proj + b_proj (f32 out); grid 512 (2 blocks/CU)
    gemm_proj_kernel<<<8 * 64, 256, 0, stream>>>(
        yb, WpT, b_proj, out, Cn, Cn, 8);
}

// Round 16
// 177.125 us; speedup vs baseline: 1.3153x; 1.0690x over previous
//
#include <hip/hip_runtime.h>
#include <math.h>

// Problem constants
#define Bn 4
#define Tn 2048
#define Cn 1024
#define Hn 16
#define HDn 64
#define Mn (Bn * Tn)  // 8192 tokens

typedef unsigned short u16;
typedef unsigned int u32;
typedef __attribute__((ext_vector_type(8))) short bf16x8;        // 8 bf16 = 4 VGPRs
typedef __attribute__((ext_vector_type(8))) unsigned short us8;  // 16B chunk
typedef __attribute__((ext_vector_type(4))) float f32x4;         // 16x16 MFMA acc
typedef __attribute__((ext_vector_type(16))) float f32x16;       // 32x32 MFMA acc
typedef __attribute__((ext_vector_type(4))) unsigned int u32x4;

__device__ __forceinline__ float b2f(u16 u) {
    return __uint_as_float(((u32)u) << 16);
}
__device__ __forceinline__ u16 f2b(float f) {
    u32 u = __float_as_uint(f);
    return (u16)((u + 0x7FFFu + ((u >> 16) & 1u)) >> 16);  // RNE
}
__device__ __forceinline__ u32 cvtpk(float a, float b) {   // {lo:bf16(a), hi:bf16(b)}
    u32 d;
    asm("v_cvt_pk_bf16_f32 %0, %1, %2" : "=v"(d) : "v"(a), "v"(b));
    return d;
}
// v_permlane32_swap_b32: a[32..63] <-> b[0..31]
__device__ __forceinline__ void pswap(u32& a, u32& b) {
    asm("v_permlane32_swap_b32 %0, %1" : "+v"(a), "+v"(b));
}
__device__ __forceinline__ float max3f(float a, float b, float c) {
    float d;
    asm("v_max3_f32 %0, %1, %2, %3" : "=v"(d) : "v"(a), "v"(b), "v"(c));
    return d;
}
#define EXP2R(x) __builtin_amdgcn_exp2f(x)   // raw v_exp_f32 (|x| < 126 here)

// XCD-grouped work id from flat block id (requires gridDim.x % 8 == 0).
__device__ __forceinline__ int xcd_work(int bid, int nwg) {
    return (bid & 7) * (nwg >> 3) + (bid >> 3);
}

// global_load_lds, width 16 (literal size required)
#define GLL(srcp, dstp)                                                     \
    __builtin_amdgcn_global_load_lds(                                       \
        (const __attribute__((address_space(1))) u32*)(srcp),               \
        (__attribute__((address_space(3))) u32*)(dstp), 16, 0, 0)

// counted vmcnt waits (T4): never drain to 0 in the main loop
#define WAITCNT6() asm volatile("s_waitcnt vmcnt(6)" ::: "memory")
#define WAITCNT4() asm volatile("s_waitcnt vmcnt(4)" ::: "memory")
#define WAITCNT0() asm volatile("s_waitcnt vmcnt(0)" ::: "memory")

// ---------------------------------------------------------------------------
// fp32 -> bf16 elementwise convert (grid-stride, 2048 blocks)
// ---------------------------------------------------------------------------
__global__ __launch_bounds__(256) void cvt_f32_bf16_kernel(
    const float4* __restrict__ in, ushort4* __restrict__ out, int n4)
{
    for (int i = blockIdx.x * 256 + threadIdx.x; i < n4; i += gridDim.x * 256) {
        float4 v = in[i];
        ushort4 o;
        o.x = f2b(v.x); o.y = f2b(v.y); o.z = f2b(v.z); o.w = f2b(v.w);
        out[i] = o;
    }
}

// ---------------------------------------------------------------------------
// Combined weight transpose+convert (one launch for both weights):
// blocks 0..95  : W_attn [1024,3072] -> WaT [3072,1024]
// blocks 96..127: W_proj [1024,1024] -> WpT [1024,1024]
// 32x32 LDS tiles, 256 threads.
// ---------------------------------------------------------------------------
__global__ __launch_bounds__(256) void transpose_both_kernel(
    const float* __restrict__ Wa, u16* __restrict__ WaT,
    const float* __restrict__ Wp, u16* __restrict__ WpT)
{
    __shared__ u16 t[32][33];
    const float* in; u16* out; int Cc, cb;
    if (blockIdx.x < 96) { in = Wa; out = WaT; Cc = 3 * Cn; cb = blockIdx.x; }
    else                 { in = Wp; out = WpT; Cc = Cn;     cb = blockIdx.x - 96; }
    const int c0 = cb * 32, r0 = blockIdx.y * 32;   // R = 1024 rows for both
    const int tx = threadIdx.x & 31, ty = threadIdx.x >> 5;  // 32 x 8
    #pragma unroll
    for (int i = 0; i < 32; i += 8)
        t[ty + i][tx] = f2b(in[(size_t)(r0 + ty + i) * Cc + c0 + tx]);
    __syncthreads();
    #pragma unroll
    for (int i = 0; i < 32; i += 8)
        out[(size_t)(c0 + ty + i) * Cn + r0 + tx] = t[tx][ty + i];
}

// ---------------------------------------------------------------------------
// QKV GEMM (R12-verified, 83.5us): 128x256 block, BK=32, 4 waves (2Mx2N),
// wave tile 64x128. Triple-buffered LDS, counted vmcnt(6), one s_barrier per
// K-step. Q/K cols -> qkvb rows; V cols (>=2048) -> vT[b][c][t] transposed.
// Grid 64x12 = 768. setprio kept (R12 exact).
// ---------------------------------------------------------------------------
__global__ __launch_bounds__(256, 2) void gemm_qkv_kernel(
    const u16* __restrict__ A, const u16* __restrict__ BT,
    const float* __restrict__ bias,
    u16* __restrict__ outb, u16* __restrict__ vTout,
    int N, int K, int nx)
{
    __shared__ u16 Al[3][128 * 32];
    __shared__ u16 Bl[3][256 * 32];

    const int tid = threadIdx.x;
    const int workid = xcd_work(blockIdx.x, gridDim.x);
    const int brow = (workid / nx) * 128;
    const int bcol = (workid % nx) * 256;
    const int w  = tid >> 6;
    const int wr = w >> 1, wc = w & 1;
    const int l  = tid & 63;
    const int lr = l & 15;
    const int lk = (l >> 4) << 3;

    const int sr = l >> 2;
    const int sc = (l & 3) << 3;

    f32x4 acc[4][8];
    #pragma unroll
    for (int m = 0; m < 4; ++m)
        #pragma unroll
        for (int n = 0; n < 8; ++n) acc[m][n] = (f32x4){0.f, 0.f, 0.f, 0.f};

    #define STAGE_G(k0, bufi)                                                   \
        do {                                                                    \
            GLL(&A [(size_t)(brow + 32 * w +      sr) * K + (k0) + sc],         \
                &Al[bufi][(32 * w) * 32]);                                      \
            GLL(&A [(size_t)(brow + 32 * w + 16 + sr) * K + (k0) + sc],         \
                &Al[bufi][(32 * w + 16) * 32]);                                 \
            GLL(&BT[(size_t)(bcol + 64 * w +      sr) * K + (k0) + sc],         \
                &Bl[bufi][(64 * w) * 32]);                                      \
            GLL(&BT[(size_t)(bcol + 64 * w + 16 + sr) * K + (k0) + sc],         \
                &Bl[bufi][(64 * w + 16) * 32]);                                 \
            GLL(&BT[(size_t)(bcol + 64 * w + 32 + sr) * K + (k0) + sc],         \
                &Bl[bufi][(64 * w + 32) * 32]);                                 \
            GLL(&BT[(size_t)(bcol + 64 * w + 48 + sr) * K + (k0) + sc],         \
                &Bl[bufi][(64 * w + 48) * 32]);                                 \
        } while (0)

    const int T = K >> 5;
    STAGE_G(0, 0);
    STAGE_G(32, 1);

    int cur = 0;
    for (int t = 0; t < T; ++t) {
        if (t < T - 1) WAITCNT6();
        else           WAITCNT0();
        __builtin_amdgcn_s_barrier();

        if (t + 2 < T) {
            const int nb = cur + 2 >= 3 ? cur - 1 : cur + 2;
            STAGE_G((t + 2) << 5, nb);
        }

        bf16x8 a[4], b[8];
        #pragma unroll
        for (int m = 0; m < 4; ++m)
            a[m] = *(const bf16x8*)&Al[cur][(wr * 64 + m * 16 + lr) * 32 + lk];
        #pragma unroll
        for (int n = 0; n < 8; ++n)
            b[n] = *(const bf16x8*)&Bl[cur][(wc * 128 + n * 16 + lr) * 32 + lk];

        __builtin_amdgcn_s_setprio(1);
        #pragma unroll
        for (int m = 0; m < 4; ++m)
            #pragma unroll
            for (int n = 0; n < 8; ++n)
                acc[m][n] = __builtin_amdgcn_mfma_f32_16x16x32_bf16(
                    a[m], b[n], acc[m][n], 0, 0, 0);
        __builtin_amdgcn_s_setprio(0);

        cur = cur == 2 ? 0 : cur + 1;
    }
    #undef STAGE_G

    // Epilogue. C/D layout: col = lane&15, row = (lane>>4)*4 + reg.
    const int orow0 = brow + wr * 64 + ((l >> 4) << 2);
    const int ocol0 = bcol + wc * 128 + lr;
    if (bcol >= 2048) {
        #pragma unroll
        for (int n = 0; n < 8; ++n) {
            const int c = ocol0 + n * 16 - 2048;
            const float bv = bias[ocol0 + n * 16];
            #pragma unroll
            for (int m = 0; m < 4; ++m) {
                const int row0 = orow0 + m * 16;
                const int bb = row0 >> 11, t0 = row0 & 2047;
                ushort4 pk;
                pk.x = f2b(acc[m][n][0] + bv);
                pk.y = f2b(acc[m][n][1] + bv);
                pk.z = f2b(acc[m][n][2] + bv);
                pk.w = f2b(acc[m][n][3] + bv);
                *(ushort4*)&vTout[((size_t)bb * Cn + c) * Tn + t0] = pk;
            }
        }
    } else {
        #pragma unroll
        for (int n = 0; n < 8; ++n) {
            const int col = ocol0 + n * 16;
            const float bv = bias[col];
            #pragma unroll
            for (int m = 0; m < 4; ++m) {
                #pragma unroll
                for (int r = 0; r < 4; ++r) {
                    const int row = orow0 + m * 16 + r;
                    outb[(size_t)row * N + col] = f2b(acc[m][n][r] + bv);
                }
            }
        }
    }
}

// ---------------------------------------------------------------------------
// Proj GEMM (R12-verified): 128x128, BK=32, 4 waves, 3 buffers, counted
// vmcnt(4). f32 out. Grid 8x64 = 512 (2 blocks/CU).
// ---------------------------------------------------------------------------
__global__ __launch_bounds__(256) void gemm_proj_kernel(
    const u16* __restrict__ A, const u16* __restrict__ BT,
    const float* __restrict__ bias, float* __restrict__ outf,
    int N, int K, int nx)
{
    __shared__ u16 Al[3][128 * 32];
    __shared__ u16 Bl[3][128 * 32];

    const int tid = threadIdx.x;
    const int workid = xcd_work(blockIdx.x, gridDim.x);
    const int brow = (workid / nx) * 128;
    const int bcol = (workid % nx) * 128;
    const int w  = tid >> 6;
    const int wr = w >> 1, wc = w & 1;
    const int l  = tid & 63;
    const int lr = l & 15;
    const int lk = (l >> 4) << 3;

    const int r0s = tid >> 2,            c0s = (tid & 3) << 3;
    const int r1s = (256 + tid) >> 2;
    const int d0s = (tid & 192) * 8;
    const int d1s = (256 + (tid & 192)) * 8;

    f32x4 acc[4][4];
    #pragma unroll
    for (int m = 0; m < 4; ++m)
        #pragma unroll
        for (int n = 0; n < 4; ++n) acc[m][n] = (f32x4){0.f, 0.f, 0.f, 0.f};

    #define STAGE_P(k0, bufi)                                                \
        do {                                                                 \
            GLL(&A [(size_t)(brow + r0s) * K + (k0) + c0s], &Al[bufi][d0s]); \
            GLL(&BT[(size_t)(bcol + r0s) * K + (k0) + c0s], &Bl[bufi][d0s]); \
            GLL(&A [(size_t)(brow + r1s) * K + (k0) + c0s], &Al[bufi][d1s]); \
            GLL(&BT[(size_t)(bcol + r1s) * K + (k0) + c0s], &Bl[bufi][d1s]); \
        } while (0)

    const int T = K >> 5;
    STAGE_P(0, 0);
    STAGE_P(32, 1);

    int cur = 0;
    for (int t = 0; t < T; ++t) {
        if (t < T - 1) WAITCNT4();
        else           WAITCNT0();
        __builtin_amdgcn_s_barrier();

        if (t + 2 < T) {
            const int nb = cur + 2 >= 3 ? cur - 1 : cur + 2;
            STAGE_P((t + 2) << 5, nb);
        }

        bf16x8 a[4], b[4];
        #pragma unroll
        for (int m = 0; m < 4; ++m)
            a[m] = *(const bf16x8*)&Al[cur][(wr * 64 + m * 16 + lr) * 32 + lk];
        #pragma unroll
        for (int n = 0; n < 4; ++n)
            b[n] = *(const bf16x8*)&Bl[cur][(wc * 64 + n * 16 + lr) * 32 + lk];

        __builtin_amdgcn_s_setprio(1);
        #pragma unroll
        for (int m = 0; m < 4; ++m)
            #pragma unroll
            for (int n = 0; n < 4; ++n)
                acc[m][n] = __builtin_amdgcn_mfma_f32_16x16x32_bf16(
                    a[m], b[n], acc[m][n], 0, 0, 0);
        __builtin_amdgcn_s_setprio(0);

        cur = cur == 2 ? 0 : cur + 1;
    }
    #undef STAGE_P

    const int orow0 = brow + wr * 64 + ((l >> 4) << 2);
    const int ocol0 = bcol + wc * 64 + lr;
    #pragma unroll
    for (int n = 0; n < 4; ++n) {
        const int col = ocol0 + n * 16;
        const float bv = bias[col];
        #pragma unroll
        for (int m = 0; m < 4; ++m) {
            #pragma unroll
            for (int r = 0; r < 4; ++r) {
                const int row = orow0 + m * 16 + r;
                outf[(size_t)row * N + col] = acc[m][n][r] + bv;
            }
        }
    }
}

// ---------------------------------------------------------------------------
// MFMA flash attention v8 (causal) - R12-verified exact. Paired q-tiles
// {p, 15-p} (uniform 36 kt-steps/block), grid 512 (2 blocks/CU), 32x32 MFMA,
// in-register softmax (T12), triple-buffered K/V with counted vmcnt(4),
// raw v_exp_f32, fmaf-folded scale, v_max3 tree, split l-accumulators.
// ---------------------------------------------------------------------------
__global__ __launch_bounds__(256, 2) void attn_mfma8_kernel(
    const u16* __restrict__ qkvb, const u16* __restrict__ vT,
    u16* __restrict__ yb)
{
    __shared__ u16 Kb[3][64 * 64];   // [k-row][d-chunk swizzled]
    __shared__ u16 Vb[3][64 * 64];   // [d-row][k-chunk swizzled]

    const int tid = threadIdx.x;
    const int w   = tid >> 6;        // wave 0..3
    const int l   = tid & 63;
    const int q31 = l & 31;          // q (QK^T B-col) / d (PV B-col)
    const int hi  = l >> 5;
    const int work = xcd_work(blockIdx.x, 512);
    const int pr  = work & 7;        // pair index 0..7
    const int bh  = work >> 3;       // 8 bh per XCD
    const int b   = bh >> 4, h = bh & 15;

    const float S2 = 0.18033688f;    // 0.125 * log2(e)

    const u16* Kg = qkvb + (size_t)(b * Tn) * (3 * Cn) + Cn + h * HDn;
    const u16* Vg = vT + (size_t)bh * HDn * Tn;

    const int srow = l >> 3;                   // staging row 0..7
    const int schk = ((l & 7) ^ srow) << 3;    // swizzled source chunk (u16)
    const int rloc = w * 16;                   // wave's staging row slice
    const int rsw8 = q31 & 7;                  // read-side XOR key (chunk idx)

    #define STAGE_A(kt, bufi)                                                  \
        do {                                                                   \
            _Pragma("unroll")                                                  \
            for (int jc = 0; jc < 2; ++jc) {                                   \
                const int rr = rloc + jc * 8;                                  \
                GLL(Kg + (size_t)((kt) * 64 + rr + srow) * (3 * Cn) + schk,    \
                    &Kb[bufi][rr * 64]);                                       \
                GLL(Vg + (size_t)(rr + srow) * Tn + (kt) * 64 + schk,          \
                    &Vb[bufi][rr * 64]);                                       \
            }                                                                  \
        } while (0)

    #pragma unroll 1
    for (int half = 0; half < 2; ++half) {
        const int qt = half ? (15 - pr) : pr;   // 128-row tile index
        const int ktmax = 2 * qt + 2;
        const int qrow0 = qt * 128 + w * 32;    // wave's first q row
        const int qglob = qrow0 + q31;          // this lane's q row

        // Q B-frags: qf[c] = Q[qglob][c*16 + hi*8 .. +7]
        const u16* Qp = qkvb + (size_t)(b * Tn + qglob) * (3 * Cn)
                        + h * HDn + hi * 8;
        bf16x8 qf[4];
        #pragma unroll
        for (int c = 0; c < 4; ++c) qf[c] = *(const bf16x8*)(Qp + c * 16);

        f32x16 O0, O1;
        #pragma unroll
        for (int r = 0; r < 16; ++r) { O0[r] = 0.f; O1[r] = 0.f; }
        float m = -INFINITY, ls = 0.f;

        STAGE_A(0, 0);
        STAGE_A(1, 1);

        int cur = 0;
        for (int kt = 0; kt < ktmax; ++kt) {
            if (kt < ktmax - 1) WAITCNT4();
            else                WAITCNT0();
            __builtin_amdgcn_s_barrier();

            if (kt + 2 < ktmax) {
                const int nb = cur + 2 >= 3 ? cur - 1 : cur + 2;
                STAGE_A(kt + 2, nb);
            }
            const u16* Kc = Kb[cur];
            const u16* Vc = Vb[cur];

            if (kt * 64 <= qrow0 + 31) {   // wave has unmasked work
                // S^T = K Q^T : two 32x32 tiles (k 0..31, 32..63)
                f32x16 S0, S1;
                #pragma unroll
                for (int r = 0; r < 16; ++r) { S0[r] = 0.f; S1[r] = 0.f; }
                __builtin_amdgcn_s_setprio(1);
                #pragma unroll
                for (int c = 0; c < 4; ++c) {
                    const int co = ((2 * c + hi) ^ rsw8) << 3;
                    const bf16x8 k0 = *(const bf16x8*)&Kc[q31 * 64 + co];
                    const bf16x8 k1 = *(const bf16x8*)&Kc[(32 + q31) * 64 + co];
                    S0 = __builtin_amdgcn_mfma_f32_32x32x16_bf16(k0, qf[c], S0, 0, 0, 0);
                    S1 = __builtin_amdgcn_mfma_f32_32x32x16_bf16(k1, qf[c], S1, 0, 0, 0);
                }
                __builtin_amdgcn_s_setprio(0);

                // causal mask (diagonal-straddling steps only)
                if (kt * 64 + 63 > qrow0) {
                    #pragma unroll
                    for (int r = 0; r < 16; ++r) {
                        const int kl = kt * 64 + (r & 3) + 8 * (r >> 2) + 4 * hi;
                        if (kl > qglob)      S0[r] = -INFINITY;
                        if (kl + 32 > qglob) S1[r] = -INFINITY;
                    }
                }

                // row max: v_max3 tree (depth 4) + 1 cross-half shuffle
                float a0 = max3f(S0[0],  S0[1],  S0[2]);
                float a1 = max3f(S0[3],  S0[4],  S0[5]);
                float a2 = max3f(S0[6],  S0[7],  S0[8]);
                float a3 = max3f(S0[9],  S0[10], S0[11]);
                float a4 = max3f(S0[12], S0[13], S0[14]);
                float a5 = max3f(S0[15], S1[0],  S1[1]);
                float a6 = max3f(S1[2],  S1[3],  S1[4]);
                float a7 = max3f(S1[5],  S1[6],  S1[7]);
                float a8 = max3f(S1[8],  S1[9],  S1[10]);
                float a9 = max3f(S1[11], S1[12], S1[13]);
                float aA = fmaxf(S1[14], S1[15]);
                float b0 = max3f(a0, a1, a2);
                float b1 = max3f(a3, a4, a5);
                float b2 = max3f(a6, a7, a8);
                float b3 = fmaxf(a9, aA);
                float mt = fmaxf(fmaxf(b0, b1), fmaxf(b2, b3));
                mt = fmaxf(mt, __shfl_xor(mt, 32));

                // defer-max (first active step always triggers: m = -inf)
                float lscale = 1.f;
                if (__any(mt > m + 64.f)) {
                    const float mn = fmaxf(m, mt);
                    const float alpha = EXP2R((m - mn) * S2);
                    m = mn; lscale = alpha;
                    #pragma unroll
                    for (int r = 0; r < 16; ++r) {
                        const int qloc = (r & 3) + 8 * (r >> 2) + 4 * hi;
                        const float ar = __shfl(alpha, qloc);
                        O0[r] *= ar; O1[r] *= ar;
                    }
                }

                // P = exp2(S*S2 - m*S2) via fmaf + raw v_exp_f32
                const float nms2 = -m * S2;
                float lt0 = 0.f, lt1 = 0.f;
                u32 w0[8], w1[8];
                #pragma unroll
                for (int i = 0; i < 8; ++i) {
                    const float p0 = EXP2R(fmaf(S0[2 * i],     S2, nms2));
                    const float p1 = EXP2R(fmaf(S0[2 * i + 1], S2, nms2));
                    const float p2 = EXP2R(fmaf(S1[2 * i],     S2, nms2));
                    const float p3 = EXP2R(fmaf(S1[2 * i + 1], S2, nms2));
                    lt0 += (p0 + p1);
                    lt1 += (p2 + p3);
                    w0[i] = cvtpk(p0, p1);
                    w1[i] = cvtpk(p2, p3);
                }
                float lt = lt0 + lt1;
                lt += __shfl_xor(lt, 32);
                ls = ls * lscale + lt;

                // O += P @ V : assemble A-frags via permlane32_swap, B from Vs
                __builtin_amdgcn_s_setprio(1);
                #pragma unroll
                for (int t2 = 0; t2 < 2; ++t2) {
                    #pragma unroll
                    for (int c1 = 0; c1 < 2; ++c1) {
                        u32 a0w = t2 ? w1[4 * c1 + 0] : w0[4 * c1 + 0];
                        u32 b0w = t2 ? w1[4 * c1 + 2] : w0[4 * c1 + 2];
                        u32 a1w = t2 ? w1[4 * c1 + 1] : w0[4 * c1 + 1];
                        u32 b1w = t2 ? w1[4 * c1 + 3] : w0[4 * c1 + 3];
                        pswap(a0w, b0w);   // -> frag words 0 and 2
                        pswap(a1w, b1w);   // -> frag words 1 and 3
                        u32x4 fr; fr.x = a0w; fr.y = a1w; fr.z = b0w; fr.w = b1w;
                        const bf16x8 pf = __builtin_bit_cast(bf16x8, fr);
                        const int c = t2 * 2 + c1;
                        const int co = ((2 * c + hi) ^ rsw8) << 3;
                        const bf16x8 v0 = *(const bf16x8*)&Vc[q31 * 64 + co];
                        const bf16x8 v1 = *(const bf16x8*)&Vc[(32 + q31) * 64 + co];
                        O0 = __builtin_amdgcn_mfma_f32_32x32x16_bf16(pf, v0, O0, 0, 0, 0);
                        O1 = __builtin_amdgcn_mfma_f32_32x32x16_bf16(pf, v1, O1, 0, 0, 0);
                    }
                }
                __builtin_amdgcn_s_setprio(0);
            }

            cur = cur == 2 ? 0 : cur + 1;
        }

        // all waves done with LDS before next half's prologue restages
        __builtin_amdgcn_s_barrier();

        // epilogue: O row r -> q = qrow0 + (r&3)+8*(r>>2)+4*hi, col = d
        #pragma unroll
        for (int r = 0; r < 16; ++r) {
            const int qloc = (r & 3) + 8 * (r >> 2) + 4 * hi;
            const float inv = __builtin_amdgcn_rcpf(__shfl(ls, qloc));
            u16* yp = yb + (size_t)(b * Tn + qrow0 + qloc) * Cn + h * HDn + q31;
            yp[0]  = f2b(O0[r] * inv);
            yp[32] = f2b(O1[r] * inv);
        }
    }
    #undef STAGE_A
}

// ---------------------------------------------------------------------------
extern "C" void kernel_launch(void* const* d_in, const int* in_sizes, int n_in,
                              void* d_out, int out_size, void* d_ws, size_t ws_size,
                              hipStream_t stream)
{
    const float* x      = (const float*)d_in[0];
    const float* W_attn = (const float*)d_in[1];
    const float* b_attn = (const float*)d_in[2];
    const float* W_proj = (const float*)d_in[3];
    const float* b_proj = (const float*)d_in[4];
    float* out = (float*)d_out;

    // Workspace (bf16): xb | WaT | WpT | qkvb | yb | vT  (~108 MB)
    u16* xb   = (u16*)d_ws;
    u16* WaT  = xb   + (size_t)Mn * Cn;
    u16* WpT  = WaT  + (size_t)3 * Cn * Cn;
    u16* qkvb = WpT  + (size_t)Cn * Cn;
    u16* yb   = qkvb + (size_t)Mn * 3 * Cn;
    u16* vT   = yb   + (size_t)Mn * Cn;

    cvt_f32_bf16_kernel<<<2048, 256, 0, stream>>>(
        (const float4*)x, (ushort4*)xb, Mn * Cn / 4);

    // both weight transposes in one launch (blocks 0-95: W_attn, 96-127: W_proj)
    transpose_both_kernel<<<dim3(128, Cn / 32), 256, 0, stream>>>(
        W_attn, WaT, W_proj, WpT);

    // qkv = x @ W_attn + b_attn; Q/K -> qkvb rows, V -> vT (fused transpose)
    gemm_qkv_kernel<<<64 * 12, 256, 0, stream>>>(
        xb, WaT, b_attn, qkvb, vT, 3 * Cn, Cn, 12);

    // causal MFMA attention -> yb (bf16); grid 512 paired, XCD-grouped
    attn_mfma8_kernel<<<512, 256, 0, stream>>>(qkvb, vT, yb);

    // out = y @ W_proj + b_proj (f32 out); grid 512 (2 blocks/CU)
    gemm_proj_kernel<<<8 * 64, 256, 0, stream>>>(
        yb, WpT, b_proj, out, Cn, Cn, 8);
}

// Round 17
// 176.528 us; speedup vs baseline: 1.3198x; 1.0034x over previous
//
#include <hip/hip_runtime.h>
#include <math.h>

// Problem constants
#define Bn 4
#define Tn 2048
#define Cn 1024
#define Hn 16
#define HDn 64
#define Mn (Bn * Tn)  // 8192 tokens

typedef unsigned short u16;
typedef unsigned int u32;
typedef __attribute__((ext_vector_type(8))) short bf16x8;        // 8 bf16 = 4 VGPRs
typedef __attribute__((ext_vector_type(8))) unsigned short us8;  // 16B chunk
typedef __attribute__((ext_vector_type(4))) float f32x4;         // 16x16 MFMA acc
typedef __attribute__((ext_vector_type(16))) float f32x16;       // 32x32 MFMA acc
typedef __attribute__((ext_vector_type(4))) unsigned int u32x4;

__device__ __forceinline__ float b2f(u16 u) {
    return __uint_as_float(((u32)u) << 16);
}
__device__ __forceinline__ u16 f2b(float f) {
    u32 u = __float_as_uint(f);
    return (u16)((u + 0x7FFFu + ((u >> 16) & 1u)) >> 16);  // RNE
}
__device__ __forceinline__ u32 cvtpk(float a, float b) {   // {lo:bf16(a), hi:bf16(b)}
    u32 d;
    asm("v_cvt_pk_bf16_f32 %0, %1, %2" : "=v"(d) : "v"(a), "v"(b));
    return d;
}
// v_permlane32_swap_b32: a[32..63] <-> b[0..31]
__device__ __forceinline__ void pswap(u32& a, u32& b) {
    asm("v_permlane32_swap_b32 %0, %1" : "+v"(a), "+v"(b));
}
__device__ __forceinline__ float max3f(float a, float b, float c) {
    float d;
    asm("v_max3_f32 %0, %1, %2, %3" : "=v"(d) : "v"(a), "v"(b), "v"(c));
    return d;
}
#define EXP2R(x) __builtin_amdgcn_exp2f(x)   // raw v_exp_f32 (|x| < 126 here)

// XCD-grouped work id from flat block id (requires gridDim.x % 8 == 0).
__device__ __forceinline__ int xcd_work(int bid, int nwg) {
    return (bid & 7) * (nwg >> 3) + (bid >> 3);
}

// global_load_lds, width 16 (literal size required)
#define GLL(srcp, dstp)                                                     \
    __builtin_amdgcn_global_load_lds(                                       \
        (const __attribute__((address_space(1))) u32*)(srcp),               \
        (__attribute__((address_space(3))) u32*)(dstp), 16, 0, 0)

// counted vmcnt waits (T4): never drain to 0 in the main loop
#define WAITCNT6() asm volatile("s_waitcnt vmcnt(6)" ::: "memory")
#define WAITCNT4() asm volatile("s_waitcnt vmcnt(4)" ::: "memory")
#define WAITCNT0() asm volatile("s_waitcnt vmcnt(0)" ::: "memory")

// ---------------------------------------------------------------------------
// Combined prep kernel (ONE launch):
//   blocks [0,2048)      : x fp32 -> xb bf16 (grid-stride over 2M float4)
//   blocks [2048,5120)   : W_attn [1024,3072] -> WaT [3072,1024] (32x32 tiles)
//   blocks [5120,6144)   : W_proj [1024,1024] -> WpT [1024,1024]
// The two memory-bound phases share HBM BW concurrently.
// ---------------------------------------------------------------------------
__global__ __launch_bounds__(256) void prep_kernel(
    const float4* __restrict__ x4, ushort4* __restrict__ xb4, int n4,
    const float* __restrict__ Wa, u16* __restrict__ WaT,
    const float* __restrict__ Wp, u16* __restrict__ WpT)
{
    __shared__ u16 t[32][33];
    const int bid = blockIdx.x;
    if (bid < 2048) {
        for (int i = bid * 256 + threadIdx.x; i < n4; i += 2048 * 256) {
            float4 v = x4[i];
            ushort4 o;
            o.x = f2b(v.x); o.y = f2b(v.y); o.z = f2b(v.z); o.w = f2b(v.w);
            xb4[i] = o;
        }
        return;
    }
    const float* in; u16* out; int Cc, cb, rb;
    if (bid < 5120) {
        const int b2 = bid - 2048;            // 3072 = 96 cols x 32 rows
        in = Wa; out = WaT; Cc = 3 * Cn; cb = b2 % 96; rb = b2 / 96;
    } else {
        const int b3 = bid - 5120;            // 1024 = 32 cols x 32 rows
        in = Wp; out = WpT; Cc = Cn;     cb = b3 & 31; rb = b3 >> 5;
    }
    const int c0 = cb * 32, r0 = rb * 32;
    const int tx = threadIdx.x & 31, ty = threadIdx.x >> 5;  // 32 x 8
    #pragma unroll
    for (int i = 0; i < 32; i += 8)
        t[ty + i][tx] = f2b(in[(size_t)(r0 + ty + i) * Cc + c0 + tx]);
    __syncthreads();
    #pragma unroll
    for (int i = 0; i < 32; i += 8)
        out[(size_t)(c0 + ty + i) * Cn + r0 + tx] = t[tx][ty + i];
}

// ---------------------------------------------------------------------------
// QKV GEMM (R12/R16-verified, 83.5us): 128x256 block, BK=32, 4 waves (2Mx2N),
// wave tile 64x128. Triple-buffered LDS, counted vmcnt(6), one s_barrier per
// K-step. Q/K cols -> qkvb rows; V cols (>=2048) -> vT[b][c][t] transposed.
// Grid 64x12 = 768.
// ---------------------------------------------------------------------------
__global__ __launch_bounds__(256, 2) void gemm_qkv_kernel(
    const u16* __restrict__ A, const u16* __restrict__ BT,
    const float* __restrict__ bias,
    u16* __restrict__ outb, u16* __restrict__ vTout,
    int N, int K, int nx)
{
    __shared__ u16 Al[3][128 * 32];
    __shared__ u16 Bl[3][256 * 32];

    const int tid = threadIdx.x;
    const int workid = xcd_work(blockIdx.x, gridDim.x);
    const int brow = (workid / nx) * 128;
    const int bcol = (workid % nx) * 256;
    const int w  = tid >> 6;
    const int wr = w >> 1, wc = w & 1;
    const int l  = tid & 63;
    const int lr = l & 15;
    const int lk = (l >> 4) << 3;

    const int sr = l >> 2;
    const int sc = (l & 3) << 3;

    f32x4 acc[4][8];
    #pragma unroll
    for (int m = 0; m < 4; ++m)
        #pragma unroll
        for (int n = 0; n < 8; ++n) acc[m][n] = (f32x4){0.f, 0.f, 0.f, 0.f};

    #define STAGE_G(k0, bufi)                                                   \
        do {                                                                    \
            GLL(&A [(size_t)(brow + 32 * w +      sr) * K + (k0) + sc],         \
                &Al[bufi][(32 * w) * 32]);                                      \
            GLL(&A [(size_t)(brow + 32 * w + 16 + sr) * K + (k0) + sc],         \
                &Al[bufi][(32 * w + 16) * 32]);                                 \
            GLL(&BT[(size_t)(bcol + 64 * w +      sr) * K + (k0) + sc],         \
                &Bl[bufi][(64 * w) * 32]);                                      \
            GLL(&BT[(size_t)(bcol + 64 * w + 16 + sr) * K + (k0) + sc],         \
                &Bl[bufi][(64 * w + 16) * 32]);                                 \
            GLL(&BT[(size_t)(bcol + 64 * w + 32 + sr) * K + (k0) + sc],         \
                &Bl[bufi][(64 * w + 32) * 32]);                                 \
            GLL(&BT[(size_t)(bcol + 64 * w + 48 + sr) * K + (k0) + sc],         \
                &Bl[bufi][(64 * w + 48) * 32]);                                 \
        } while (0)

    const int T = K >> 5;
    STAGE_G(0, 0);
    STAGE_G(32, 1);

    int cur = 0;
    for (int t = 0; t < T; ++t) {
        if (t < T - 1) WAITCNT6();
        else           WAITCNT0();
        __builtin_amdgcn_s_barrier();

        if (t + 2 < T) {
            const int nb = cur + 2 >= 3 ? cur - 1 : cur + 2;
            STAGE_G((t + 2) << 5, nb);
        }

        bf16x8 a[4], b[8];
        #pragma unroll
        for (int m = 0; m < 4; ++m)
            a[m] = *(const bf16x8*)&Al[cur][(wr * 64 + m * 16 + lr) * 32 + lk];
        #pragma unroll
        for (int n = 0; n < 8; ++n)
            b[n] = *(const bf16x8*)&Bl[cur][(wc * 128 + n * 16 + lr) * 32 + lk];

        __builtin_amdgcn_s_setprio(1);
        #pragma unroll
        for (int m = 0; m < 4; ++m)
            #pragma unroll
            for (int n = 0; n < 8; ++n)
                acc[m][n] = __builtin_amdgcn_mfma_f32_16x16x32_bf16(
                    a[m], b[n], acc[m][n], 0, 0, 0);
        __builtin_amdgcn_s_setprio(0);

        cur = cur == 2 ? 0 : cur + 1;
    }
    #undef STAGE_G

    // Epilogue. C/D layout: col = lane&15, row = (lane>>4)*4 + reg.
    const int orow0 = brow + wr * 64 + ((l >> 4) << 2);
    const int ocol0 = bcol + wc * 128 + lr;
    if (bcol >= 2048) {
        #pragma unroll
        for (int n = 0; n < 8; ++n) {
            const int c = ocol0 + n * 16 - 2048;
            const float bv = bias[ocol0 + n * 16];
            #pragma unroll
            for (int m = 0; m < 4; ++m) {
                const int row0 = orow0 + m * 16;
                const int bb = row0 >> 11, t0 = row0 & 2047;
                ushort4 pk;
                pk.x = f2b(acc[m][n][0] + bv);
                pk.y = f2b(acc[m][n][1] + bv);
                pk.z = f2b(acc[m][n][2] + bv);
                pk.w = f2b(acc[m][n][3] + bv);
                *(ushort4*)&vTout[((size_t)bb * Cn + c) * Tn + t0] = pk;
            }
        }
    } else {
        #pragma unroll
        for (int n = 0; n < 8; ++n) {
            const int col = ocol0 + n * 16;
            const float bv = bias[col];
            #pragma unroll
            for (int m = 0; m < 4; ++m) {
                #pragma unroll
                for (int r = 0; r < 4; ++r) {
                    const int row = orow0 + m * 16 + r;
                    outb[(size_t)row * N + col] = f2b(acc[m][n][r] + bv);
                }
            }
        }
    }
}

// ---------------------------------------------------------------------------
// Proj GEMM (R12/R16-verified): 128x128, BK=32, 4 waves, 3 buffers, counted
// vmcnt(4). f32 out. Grid 8x64 = 512 (2 blocks/CU).
// ---------------------------------------------------------------------------
__global__ __launch_bounds__(256) void gemm_proj_kernel(
    const u16* __restrict__ A, const u16* __restrict__ BT,
    const float* __restrict__ bias, float* __restrict__ outf,
    int N, int K, int nx)
{
    __shared__ u16 Al[3][128 * 32];
    __shared__ u16 Bl[3][128 * 32];

    const int tid = threadIdx.x;
    const int workid = xcd_work(blockIdx.x, gridDim.x);
    const int brow = (workid / nx) * 128;
    const int bcol = (workid % nx) * 128;
    const int w  = tid >> 6;
    const int wr = w >> 1, wc = w & 1;
    const int l  = tid & 63;
    const int lr = l & 15;
    const int lk = (l >> 4) << 3;

    const int r0s = tid >> 2,            c0s = (tid & 3) << 3;
    const int r1s = (256 + tid) >> 2;
    const int d0s = (tid & 192) * 8;
    const int d1s = (256 + (tid & 192)) * 8;

    f32x4 acc[4][4];
    #pragma unroll
    for (int m = 0; m < 4; ++m)
        #pragma unroll
        for (int n = 0; n < 4; ++n) acc[m][n] = (f32x4){0.f, 0.f, 0.f, 0.f};

    #define STAGE_P(k0, bufi)                                                \
        do {                                                                 \
            GLL(&A [(size_t)(brow + r0s) * K + (k0) + c0s], &Al[bufi][d0s]); \
            GLL(&BT[(size_t)(bcol + r0s) * K + (k0) + c0s], &Bl[bufi][d0s]); \
            GLL(&A [(size_t)(brow + r1s) * K + (k0) + c0s], &Al[bufi][d1s]); \
            GLL(&BT[(size_t)(bcol + r1s) * K + (k0) + c0s], &Bl[bufi][d1s]); \
        } while (0)

    const int T = K >> 5;
    STAGE_P(0, 0);
    STAGE_P(32, 1);

    int cur = 0;
    for (int t = 0; t < T; ++t) {
        if (t < T - 1) WAITCNT4();
        else           WAITCNT0();
        __builtin_amdgcn_s_barrier();

        if (t + 2 < T) {
            const int nb = cur + 2 >= 3 ? cur - 1 : cur + 2;
            STAGE_P((t + 2) << 5, nb);
        }

        bf16x8 a[4], b[4];
        #pragma unroll
        for (int m = 0; m < 4; ++m)
            a[m] = *(const bf16x8*)&Al[cur][(wr * 64 + m * 16 + lr) * 32 + lk];
        #pragma unroll
        for (int n = 0; n < 4; ++n)
            b[n] = *(const bf16x8*)&Bl[cur][(wc * 64 + n * 16 + lr) * 32 + lk];

        __builtin_amdgcn_s_setprio(1);
        #pragma unroll
        for (int m = 0; m < 4; ++m)
            #pragma unroll
            for (int n = 0; n < 4; ++n)
                acc[m][n] = __builtin_amdgcn_mfma_f32_16x16x32_bf16(
                    a[m], b[n], acc[m][n], 0, 0, 0);
        __builtin_amdgcn_s_setprio(0);

        cur = cur == 2 ? 0 : cur + 1;
    }
    #undef STAGE_P

    const int orow0 = brow + wr * 64 + ((l >> 4) << 2);
    const int ocol0 = bcol + wc * 64 + lr;
    #pragma unroll
    for (int n = 0; n < 4; ++n) {
        const int col = ocol0 + n * 16;
        const float bv = bias[col];
        #pragma unroll
        for (int m = 0; m < 4; ++m) {
            #pragma unroll
            for (int r = 0; r < 4; ++r) {
                const int row = orow0 + m * 16 + r;
                outf[(size_t)row * N + col] = acc[m][n][r] + bv;
            }
        }
    }
}

// ---------------------------------------------------------------------------
// MFMA flash attention v8 (causal) - R12/R16-verified exact. Paired q-tiles
// {p, 15-p}, grid 512 (2 blocks/CU), 32x32 MFMA, in-register softmax (T12),
// triple-buffered K/V with counted vmcnt(4), raw v_exp_f32, fmaf-folded
// scale, v_max3 tree, split l-accumulators.
// ---------------------------------------------------------------------------
__global__ __launch_bounds__(256, 2) void attn_mfma8_kernel(
    const u16* __restrict__ qkvb, const u16* __restrict__ vT,
    u16* __restrict__ yb)
{
    __shared__ u16 Kb[3][64 * 64];   // [k-row][d-chunk swizzled]
    __shared__ u16 Vb[3][64 * 64];   // [d-row][k-chunk swizzled]

    const int tid = threadIdx.x;
    const int w   = tid >> 6;        // wave 0..3
    const int l   = tid & 63;
    const int q31 = l & 31;          // q (QK^T B-col) / d (PV B-col)
    const int hi  = l >> 5;
    const int work = xcd_work(blockIdx.x, 512);
    const int pr  = work & 7;        // pair index 0..7
    const int bh  = work >> 3;       // 8 bh per XCD
    const int b   = bh >> 4, h = bh & 15;

    const float S2 = 0.18033688f;    // 0.125 * log2(e)

    const u16* Kg = qkvb + (size_t)(b * Tn) * (3 * Cn) + Cn + h * HDn;
    const u16* Vg = vT + (size_t)bh * HDn * Tn;

    const int srow = l >> 3;                   // staging row 0..7
    const int schk = ((l & 7) ^ srow) << 3;    // swizzled source chunk (u16)
    const int rloc = w * 16;                   // wave's staging row slice
    const int rsw8 = q31 & 7;                  // read-side XOR key (chunk idx)

    #define STAGE_A(kt, bufi)                                                  \
        do {                                                                   \
            _Pragma("unroll")                                                  \
            for (int jc = 0; jc < 2; ++jc) {                                   \
                const int rr = rloc + jc * 8;                                  \
                GLL(Kg + (size_t)((kt) * 64 + rr + srow) * (3 * Cn) + schk,    \
                    &Kb[bufi][rr * 64]);                                       \
                GLL(Vg + (size_t)(rr + srow) * Tn + (kt) * 64 + schk,          \
                    &Vb[bufi][rr * 64]);                                       \
            }                                                                  \
        } while (0)

    #pragma unroll 1
    for (int half = 0; half < 2; ++half) {
        const int qt = half ? (15 - pr) : pr;   // 128-row tile index
        const int ktmax = 2 * qt + 2;
        const int qrow0 = qt * 128 + w * 32;    // wave's first q row
        const int qglob = qrow0 + q31;          // this lane's q row

        // Q B-frags: qf[c] = Q[qglob][c*16 + hi*8 .. +7]
        const u16* Qp = qkvb + (size_t)(b * Tn + qglob) * (3 * Cn)
                        + h * HDn + hi * 8;
        bf16x8 qf[4];
        #pragma unroll
        for (int c = 0; c < 4; ++c) qf[c] = *(const bf16x8*)(Qp + c * 16);

        f32x16 O0, O1;
        #pragma unroll
        for (int r = 0; r < 16; ++r) { O0[r] = 0.f; O1[r] = 0.f; }
        float m = -INFINITY, ls = 0.f;

        STAGE_A(0, 0);
        STAGE_A(1, 1);

        int cur = 0;
        for (int kt = 0; kt < ktmax; ++kt) {
            if (kt < ktmax - 1) WAITCNT4();
            else                WAITCNT0();
            __builtin_amdgcn_s_barrier();

            if (kt + 2 < ktmax) {
                const int nb = cur + 2 >= 3 ? cur - 1 : cur + 2;
                STAGE_A(kt + 2, nb);
            }
            const u16* Kc = Kb[cur];
            const u16* Vc = Vb[cur];

            if (kt * 64 <= qrow0 + 31) {   // wave has unmasked work
                // S^T = K Q^T : two 32x32 tiles (k 0..31, 32..63)
                f32x16 S0, S1;
                #pragma unroll
                for (int r = 0; r < 16; ++r) { S0[r] = 0.f; S1[r] = 0.f; }
                __builtin_amdgcn_s_setprio(1);
                #pragma unroll
                for (int c = 0; c < 4; ++c) {
                    const int co = ((2 * c + hi) ^ rsw8) << 3;
                    const bf16x8 k0 = *(const bf16x8*)&Kc[q31 * 64 + co];
                    const bf16x8 k1 = *(const bf16x8*)&Kc[(32 + q31) * 64 + co];
                    S0 = __builtin_amdgcn_mfma_f32_32x32x16_bf16(k0, qf[c], S0, 0, 0, 0);
                    S1 = __builtin_amdgcn_mfma_f32_32x32x16_bf16(k1, qf[c], S1, 0, 0, 0);
                }
                __builtin_amdgcn_s_setprio(0);

                // causal mask (diagonal-straddling steps only)
                if (kt * 64 + 63 > qrow0) {
                    #pragma unroll
                    for (int r = 0; r < 16; ++r) {
                        const int kl = kt * 64 + (r & 3) + 8 * (r >> 2) + 4 * hi;
                        if (kl > qglob)      S0[r] = -INFINITY;
                        if (kl + 32 > qglob) S1[r] = -INFINITY;
                    }
                }

                // row max: v_max3 tree (depth 4) + 1 cross-half shuffle
                float a0 = max3f(S0[0],  S0[1],  S0[2]);
                float a1 = max3f(S0[3],  S0[4],  S0[5]);
                float a2 = max3f(S0[6],  S0[7],  S0[8]);
                float a3 = max3f(S0[9],  S0[10], S0[11]);
                float a4 = max3f(S0[12], S0[13], S0[14]);
                float a5 = max3f(S0[15], S1[0],  S1[1]);
                float a6 = max3f(S1[2],  S1[3],  S1[4]);
                float a7 = max3f(S1[5],  S1[6],  S1[7]);
                float a8 = max3f(S1[8],  S1[9],  S1[10]);
                float a9 = max3f(S1[11], S1[12], S1[13]);
                float aA = fmaxf(S1[14], S1[15]);
                float b0 = max3f(a0, a1, a2);
                float b1 = max3f(a3, a4, a5);
                float b2 = max3f(a6, a7, a8);
                float b3 = fmaxf(a9, aA);
                float mt = fmaxf(fmaxf(b0, b1), fmaxf(b2, b3));
                mt = fmaxf(mt, __shfl_xor(mt, 32));

                // defer-max (first active step always triggers: m = -inf)
                float lscale = 1.f;
                if (__any(mt > m + 64.f)) {
                    const float mn = fmaxf(m, mt);
                    const float alpha = EXP2R((m - mn) * S2);
                    m = mn; lscale = alpha;
                    #pragma unroll
                    for (int r = 0; r < 16; ++r) {
                        const int qloc = (r & 3) + 8 * (r >> 2) + 4 * hi;
                        const float ar = __shfl(alpha, qloc);
                        O0[r] *= ar; O1[r] *= ar;
                    }
                }

                // P = exp2(S*S2 - m*S2) via fmaf + raw v_exp_f32
                const float nms2 = -m * S2;
                float lt0 = 0.f, lt1 = 0.f;
                u32 w0[8], w1[8];
                #pragma unroll
                for (int i = 0; i < 8; ++i) {
                    const float p0 = EXP2R(fmaf(S0[2 * i],     S2, nms2));
                    const float p1 = EXP2R(fmaf(S0[2 * i + 1], S2, nms2));
                    const float p2 = EXP2R(fmaf(S1[2 * i],     S2, nms2));
                    const float p3 = EXP2R(fmaf(S1[2 * i + 1], S2, nms2));
                    lt0 += (p0 + p1);
                    lt1 += (p2 + p3);
                    w0[i] = cvtpk(p0, p1);
                    w1[i] = cvtpk(p2, p3);
                }
                float lt = lt0 + lt1;
                lt += __shfl_xor(lt, 32);
                ls = ls * lscale + lt;

                // O += P @ V : assemble A-frags via permlane32_swap, B from Vs
                __builtin_amdgcn_s_setprio(1);
                #pragma unroll
                for (int t2 = 0; t2 < 2; ++t2) {
                    #pragma unroll
                    for (int c1 = 0; c1 < 2; ++c1) {
                        u32 a0w = t2 ? w1[4 * c1 + 0] : w0[4 * c1 + 0];
                        u32 b0w = t2 ? w1[4 * c1 + 2] : w0[4 * c1 + 2];
                        u32 a1w = t2 ? w1[4 * c1 + 1] : w0[4 * c1 + 1];
                        u32 b1w = t2 ? w1[4 * c1 + 3] : w0[4 * c1 + 3];
                        pswap(a0w, b0w);   // -> frag words 0 and 2
                        pswap(a1w, b1w);   // -> frag words 1 and 3
                        u32x4 fr; fr.x = a0w; fr.y = a1w; fr.z = b0w; fr.w = b1w;
                        const bf16x8 pf = __builtin_bit_cast(bf16x8, fr);
                        const int c = t2 * 2 + c1;
                        const int co = ((2 * c + hi) ^ rsw8) << 3;
                        const bf16x8 v0 = *(const bf16x8*)&Vc[q31 * 64 + co];
                        const bf16x8 v1 = *(const bf16x8*)&Vc[(32 + q31) * 64 + co];
                        O0 = __builtin_amdgcn_mfma_f32_32x32x16_bf16(pf, v0, O0, 0, 0, 0);
                        O1 = __builtin_amdgcn_mfma_f32_32x32x16_bf16(pf, v1, O1, 0, 0, 0);
                    }
                }
                __builtin_amdgcn_s_setprio(0);
            }

            cur = cur == 2 ? 0 : cur + 1;
        }

        // all waves done with LDS before next half's prologue restages
        __builtin_amdgcn_s_barrier();

        // epilogue: O row r -> q = qrow0 + (r&3)+8*(r>>2)+4*hi, col = d
        #pragma unroll
        for (int r = 0; r < 16; ++r) {
            const int qloc = (r & 3) + 8 * (r >> 2) + 4 * hi;
            const float inv = __builtin_amdgcn_rcpf(__shfl(ls, qloc));
            u16* yp = yb + (size_t)(b * Tn + qrow0 + qloc) * Cn + h * HDn + q31;
            yp[0]  = f2b(O0[r] * inv);
            yp[32] = f2b(O1[r] * inv);
        }
    }
    #undef STAGE_A
}

// ---------------------------------------------------------------------------
extern "C" void kernel_launch(void* const* d_in, const int* in_sizes, int n_in,
                              void* d_out, int out_size, void* d_ws, size_t ws_size,
                              hipStream_t stream)
{
    const float* x      = (const float*)d_in[0];
    const float* W_attn = (const float*)d_in[1];
    const float* b_attn = (const float*)d_in[2];
    const float* W_proj = (const float*)d_in[3];
    const float* b_proj = (const float*)d_in[4];
    float* out = (float*)d_out;

    // Workspace (bf16): xb | WaT | WpT | qkvb | yb | vT  (~108 MB)
    u16* xb   = (u16*)d_ws;
    u16* WaT  = xb   + (size_t)Mn * Cn;
    u16* WpT  = WaT  + (size_t)3 * Cn * Cn;
    u16* qkvb = WpT  + (size_t)Cn * Cn;
    u16* yb   = qkvb + (size_t)Mn * 3 * Cn;
    u16* vT   = yb   + (size_t)Mn * Cn;

    // one fused prep launch: x->bf16 convert + both weight transposes
    prep_kernel<<<6144, 256, 0, stream>>>(
        (const float4*)x, (ushort4*)xb, Mn * Cn / 4,
        W_attn, WaT, W_proj, WpT);

    // qkv = x @ W_attn + b_attn; Q/K -> qkvb rows, V -> vT (fused transpose)
    gemm_qkv_kernel<<<64 * 12, 256, 0, stream>>>(
        xb, WaT, b_attn, qkvb, vT, 3 * Cn, Cn, 12);

    // causal MFMA attention -> yb (bf16); grid 512 paired, XCD-grouped
    attn_mfma8_kernel<<<512, 256, 0, stream>>>(qkvb, vT, yb);

    // out = y @ W_proj + b_proj (f32 out); grid 512 (2 blocks/CU)
    gemm_proj_kernel<<<8 * 64, 256, 0, stream>>>(
        yb, WpT, b_proj, out, Cn, Cn, 8);
}